// Round 2
// baseline (6679.230 us; speedup 1.0000x reference)
//
#include <hip/hip_runtime.h>
#include <hip/hip_bf16.h>
#include <cstdint>
#include <cstddef>

#define HD   256
#define NV   50000
#define NE   80000
#define NNZC 400000
#define FINC 512
#define NCLS 40

using bf16 = __hip_bfloat16;

constexpr int BM = 64, BN = 64, BK = 32;

// ---------- dtype helpers ----------
__device__ __forceinline__ float b2f(unsigned short u) {
    union { unsigned int i; float f; } c; c.i = ((unsigned int)u) << 16; return c.f;
}
__device__ __forceinline__ unsigned short f2b(float f) {
    union { float f; unsigned int i; } c; c.f = f;
    return (unsigned short)((c.i + 0x7FFFu + ((c.i >> 16) & 1u)) >> 16);
}
__device__ __forceinline__ float4 load4f(const float* p) { return *reinterpret_cast<const float4*>(p); }
__device__ __forceinline__ float4 load4f(const bf16* p) {
    ushort4 u = *reinterpret_cast<const ushort4*>(p);
    return make_float4(b2f(u.x), b2f(u.y), b2f(u.z), b2f(u.w));
}
__device__ __forceinline__ void store4(float* p, float4 v) { *reinterpret_cast<float4*>(p) = v; }
__device__ __forceinline__ void store4(bf16* p, float4 v) {
    ushort4 u; u.x = f2b(v.x); u.y = f2b(v.y); u.z = f2b(v.z); u.w = f2b(v.w);
    *reinterpret_cast<ushort4*>(p) = u;
}
__device__ __forceinline__ float tofl(float x) { return x; }
__device__ __forceinline__ float tofl(bf16 x) { return __bfloat162float(x); }

// ---------- capture-safe zero fill ----------
__global__ __launch_bounds__(256)
void fill0_k(unsigned int* __restrict__ p, long long n)
{
    long long i = (long long)blockIdx.x * 256 + threadIdx.x;
    long long stride = (long long)gridDim.x * 256;
    for (; i < n; i += stride) p[i] = 0u;
}

// ---------- degree histogram ----------
__global__ __launch_bounds__(256)
void deg_k(const int* __restrict__ vertex, int* __restrict__ deg, int nnz)
{
    int i = blockIdx.x * 256 + threadIdx.x;
    if (i < nnz) atomicAdd(&deg[vertex[i]], 1);
}

// ---------- tiled GEMM: C = epi(A@B + bias), A may be 0.5*(A+A2) ----------
// EPI: 0 = none, 1 = relu, 2 = deg-scale: C = deg[row]*(acc + bias)
template<int EPI, bool HALF2, class TA, class TA2, class TC>
__global__ __launch_bounds__(256)
void gemm_k(const TA* __restrict__ Ag, const TA2* __restrict__ A2g,
            const float* __restrict__ Bg, const float* __restrict__ bias,
            const int* __restrict__ deg, TC* __restrict__ Cg,
            int M, int K, int Nc)
{
    __shared__ float As[BM][BK + 4];
    __shared__ float Bs[BK][BN];

    const int t  = threadIdx.x;
    const int tx = t & 15;
    const int ty = t >> 4;
    const int bm = blockIdx.x * BM;
    const int bn = blockIdx.y * BN;

    float acc[4][4] = {};

    for (int k0 = 0; k0 < K; k0 += BK) {
        #pragma unroll
        for (int L = 0; L < 2; ++L) {
            int idx = t + L * 256;
            int r   = idx >> 3;
            int kc  = (idx & 7) << 2;
            int row = bm + r;
            float4 v = make_float4(0.f, 0.f, 0.f, 0.f);
            if (row < M) {
                v = load4f(Ag + (size_t)row * K + k0 + kc);
                if (HALF2) {
                    float4 w = load4f(A2g + (size_t)row * K + k0 + kc);
                    v.x = 0.5f * (v.x + w.x); v.y = 0.5f * (v.y + w.y);
                    v.z = 0.5f * (v.z + w.z); v.w = 0.5f * (v.w + w.w);
                }
            }
            *reinterpret_cast<float4*>(&As[r][kc]) = v;
        }
        #pragma unroll
        for (int L = 0; L < 2; ++L) {
            int idx = t + L * 256;
            int kr  = idx >> 4;
            int nc  = (idx & 15) << 2;
            float4 v = *reinterpret_cast<const float4*>(Bg + (size_t)(k0 + kr) * Nc + bn + nc);
            *reinterpret_cast<float4*>(&Bs[kr][nc]) = v;
        }
        __syncthreads();

        #pragma unroll
        for (int k = 0; k < BK; k += 4) {
            float4 a[4], b[4];
            #pragma unroll
            for (int i = 0; i < 4; ++i)
                a[i] = *reinterpret_cast<const float4*>(&As[ty * 4 + i][k]);
            #pragma unroll
            for (int j = 0; j < 4; ++j)
                b[j] = *reinterpret_cast<const float4*>(&Bs[k + j][tx * 4]);
            #pragma unroll
            for (int j = 0; j < 4; ++j) {
                #pragma unroll
                for (int i = 0; i < 4; ++i) {
                    float av = (j == 0) ? a[i].x : (j == 1) ? a[i].y : (j == 2) ? a[i].z : a[i].w;
                    acc[i][0] += av * b[j].x;
                    acc[i][1] += av * b[j].y;
                    acc[i][2] += av * b[j].z;
                    acc[i][3] += av * b[j].w;
                }
            }
        }
        __syncthreads();
    }

    float4 bv = make_float4(0.f, 0.f, 0.f, 0.f);
    if (bias) bv = *reinterpret_cast<const float4*>(bias + bn + tx * 4);
    #pragma unroll
    for (int i = 0; i < 4; ++i) {
        int row = bm + ty * 4 + i;
        if (row >= M) continue;
        float4 o;
        o.x = acc[i][0] + bv.x; o.y = acc[i][1] + bv.y;
        o.z = acc[i][2] + bv.z; o.w = acc[i][3] + bv.w;
        if (EPI == 1) {
            o.x = fmaxf(o.x, 0.f); o.y = fmaxf(o.y, 0.f);
            o.z = fmaxf(o.z, 0.f); o.w = fmaxf(o.w, 0.f);
        } else if (EPI == 2) {
            float d = (float)deg[row];
            o.x *= 0.f + d; o.y *= d; o.z *= d; o.w *= d;
            // note: bias already added above, so this is d*(acc+bias)
        }
        store4(Cg + (size_t)row * Nc + bn + tx * 4, o);
    }
}

// ---------- scatter-add rows: dst[di[i]] += src[si[i]] ----------
template<class TS>
__global__ __launch_bounds__(256)
void scatter_add_k(const TS* __restrict__ src, const int* __restrict__ si,
                   const int* __restrict__ di, float* __restrict__ dst, int nnz)
{
    int i = blockIdx.x * 4 + (threadIdx.x >> 6);
    if (i >= nnz) return;
    int lane = threadIdx.x & 63;
    int s = si[i], d = di[i];
    float4 v = load4f(src + (size_t)s * HD + lane * 4);
    float* p = dst + (size_t)d * HD + lane * 4;
    atomicAdd(p + 0, v.x);
    atomicAdd(p + 1, v.y);
    atomicAdd(p + 2, v.z);
    atomicAdd(p + 3, v.w);
}

// ---------- classifier head: out[M,40] = H[M,256] @ W[256,40] + b ----------
template<class TH>
__global__ __launch_bounds__(256)
void cls2_k(const TH* __restrict__ Hm, const float* __restrict__ W,
            const float* __restrict__ bias, float* __restrict__ out, int M)
{
    __shared__ float ws_[HD][NCLS];
    for (int i = threadIdx.x; i < HD * NCLS; i += 256)
        ws_[i / NCLS][i % NCLS] = W[i];
    __syncthreads();
    int row  = blockIdx.x * 4 + (threadIdx.x >> 6);
    int lane = threadIdx.x & 63;
    if (row >= M || lane >= NCLS) return;
    const TH* hr = Hm + (size_t)row * HD;
    float sum = bias[lane];
    #pragma unroll 8
    for (int k = 0; k < HD; ++k) sum += tofl(hr[k]) * ws_[k][lane];
    out[(size_t)row * NCLS + lane] = sum;
}

// ---------- full pipeline, feature dtype TX ----------
template<class TX>
static void run_all(const float* x_in, const int* vertex, const int* edges,
                    const float* lin_w, const float* lin_b,
                    const float* w1, const float* b1, const float* w2, const float* b2,
                    const float* w3, const float* b3,
                    const float* cw1, const float* cb1, const float* cw2, const float* cb2,
                    float* out, char* ws, hipStream_t stream)
{
    const size_t nvhd = (size_t)NV * HD, nehd = (size_t)NE * HD;
    size_t off = 0;
    TX* x0 = (TX*)(ws + off); off += nvhd * sizeof(TX);   // restart anchor
    TX* xA = (TX*)(ws + off); off += nvhd * sizeof(TX);   // layer output (in-place reuse)
    TX* E1 = (TX*)(ws + off); off += nehd * sizeof(TX);   // T1 -> Bm -> cls hidden
    float* E2 = (float*)(ws + off); off += nehd * sizeof(float); // xe -> xv (atomic tgt)
    int* deg = (int*)(ws + off);

    dim3 blk(256);
    dim3 gin((NV + BM - 1) / BM, HD / BN);   // 782 x 4
    dim3 ge((NE + BM - 1) / BM, HD / BN);    // 1250 x 4

    fill0_k<<<64, blk, 0, stream>>>((unsigned int*)deg, NV);
    deg_k<<<(NNZC + 255) / 256, blk, 0, stream>>>(vertex, deg, NNZC);

    // x0 = relu(x_in @ lin_w + lin_b)
    gemm_k<1, false, float, float, TX><<<gin, blk, 0, stream>>>(
        x_in, nullptr, lin_w, lin_b, nullptr, x0, NV, FINC, HD);

    const TX* cur = x0;
    for (int layer = 0; layer < 2; ++layer) {
        // E1 = cur @ w1 + b1
        gemm_k<0, false, TX, TX, TX><<<gin, blk, 0, stream>>>(
            cur, nullptr, w1, b1, nullptr, E1, NV, HD, HD);
        // E2(xe) = segment_sum(E1[vertex], edges)
        fill0_k<<<2048, blk, 0, stream>>>((unsigned int*)E2, (long long)nehd);
        scatter_add_k<TX><<<NNZC / 4, blk, 0, stream>>>(E1, vertex, edges, E2, NNZC);
        // E1(Bm) = xe @ w2b   (overwrites T1, which is dead)
        gemm_k<0, false, float, float, TX><<<ge, blk, 0, stream>>>(
            E2, nullptr, w2 + HD * HD, nullptr, nullptr, E1, NE, HD, HD);
        // E2(xv) = deg * (cur @ w2a + b2)   (overwrites xe, which is dead)
        gemm_k<2, false, TX, TX, float><<<gin, blk, 0, stream>>>(
            cur, nullptr, w2, b2, deg, E2, NV, HD, HD);
        // xv += segment_sum(Bm[edges], vertex)
        scatter_add_k<TX><<<NNZC / 4, blk, 0, stream>>>(E1, edges, vertex, E2, NNZC);
        // xA = relu((0.5*xv + 0.5*x0) @ w3 + b3)   (reads only E2, x0 -> safe in-place)
        gemm_k<1, true, float, TX, TX><<<gin, blk, 0, stream>>>(
            E2, x0, w3, b3, nullptr, xA, NV, HD, HD);
        cur = xA;
    }

    // classifier
    gemm_k<1, false, TX, TX, TX><<<gin, blk, 0, stream>>>(
        xA, nullptr, cw1, cb1, nullptr, E1, NV, HD, HD);
    cls2_k<TX><<<(NV + 3) / 4, blk, 0, stream>>>(E1, cw2, cb2, out, NV);
}

extern "C" void kernel_launch(void* const* d_in, const int* in_sizes, int n_in,
                              void* d_out, int out_size, void* d_ws, size_t ws_size,
                              hipStream_t stream)
{
    const float* x_in   = (const float*)d_in[0];
    const int*   vertex = (const int*)d_in[1];
    const int*   edges  = (const int*)d_in[2];
    const float* lin_w  = (const float*)d_in[3];
    const float* lin_b  = (const float*)d_in[4];
    const float* w1     = (const float*)d_in[5];
    const float* b1     = (const float*)d_in[6];
    const float* w2     = (const float*)d_in[7];
    const float* b2     = (const float*)d_in[8];
    const float* w3     = (const float*)d_in[9];
    const float* b3     = (const float*)d_in[10];
    const float* cw1    = (const float*)d_in[11];
    const float* cb1    = (const float*)d_in[12];
    const float* cw2    = (const float*)d_in[13];
    const float* cb2    = (const float*)d_in[14];
    float* out = (float*)d_out;
    (void)in_sizes; (void)n_in; (void)out_size;

    const size_t nvhd = (size_t)NV * HD, nehd = (size_t)NE * HD;
    const size_t need_f32 = (2 * nvhd + nehd) * 4 + nehd * 4 + (size_t)NV * 4; // ~266.5 MB
    const size_t need_bf  = (2 * nvhd + nehd) * 2 + nehd * 4 + (size_t)NV * 4; // ~174.3 MB

    if (ws_size >= need_f32) {
        run_all<float>(x_in, vertex, edges, lin_w, lin_b, w1, b1, w2, b2, w3, b3,
                       cw1, cb1, cw2, cb2, out, (char*)d_ws, stream);
    } else if (ws_size >= need_bf) {
        run_all<bf16>(x_in, vertex, edges, lin_w, lin_b, w1, b1, w2, b2, w3, b3,
                      cw1, cb1, cw2, cb2, out, (char*)d_ws, stream);
    }
    // else: insufficient workspace — intentionally launch nothing so the
    // harness reports a clean absmax failure (diagnostic for ws_size tier).
}

// Round 3
// 1730.170 us; speedup vs baseline: 3.8604x; 3.8604x over previous
//
#include <hip/hip_runtime.h>
#include <hip/hip_bf16.h>
#include <cstdint>
#include <cstddef>

#define HD   256
#define NV   50000
#define NE   80000
#define NNZC 400000
#define FINC 512
#define NCLS 40

using bf16 = __hip_bfloat16;

constexpr int BM = 64, BN = 64, BK = 32;

// ---------- dtype helpers ----------
__device__ __forceinline__ float b2f(unsigned short u) {
    union { unsigned int i; float f; } c; c.i = ((unsigned int)u) << 16; return c.f;
}
__device__ __forceinline__ unsigned short f2b(float f) {
    union { float f; unsigned int i; } c; c.f = f;
    return (unsigned short)((c.i + 0x7FFFu + ((c.i >> 16) & 1u)) >> 16);
}
__device__ __forceinline__ float4 load4f(const float* p) { return *reinterpret_cast<const float4*>(p); }
__device__ __forceinline__ float4 load4f(const bf16* p) {
    ushort4 u = *reinterpret_cast<const ushort4*>(p);
    return make_float4(b2f(u.x), b2f(u.y), b2f(u.z), b2f(u.w));
}
__device__ __forceinline__ void store4(float* p, float4 v) { *reinterpret_cast<float4*>(p) = v; }
__device__ __forceinline__ void store4(bf16* p, float4 v) {
    ushort4 u; u.x = f2b(v.x); u.y = f2b(v.y); u.z = f2b(v.z); u.w = f2b(v.w);
    *reinterpret_cast<ushort4*>(p) = u;
}
__device__ __forceinline__ float tofl(float x) { return x; }
__device__ __forceinline__ float tofl(bf16 x) { return __bfloat162float(x); }

// ---------- capture-safe zero fill ----------
__global__ __launch_bounds__(256)
void fill0_k(unsigned int* __restrict__ p, long long n)
{
    long long i = (long long)blockIdx.x * 256 + threadIdx.x;
    long long stride = (long long)gridDim.x * 256;
    for (; i < n; i += stride) p[i] = 0u;
}

// ---------- combined histogram: cnt_v[vertex[i]]++, cnt_e[edges[i]]++ ----------
__global__ __launch_bounds__(256)
void hist_k(const int* __restrict__ vertex, const int* __restrict__ edges,
            int* __restrict__ cnt_v, int* __restrict__ cnt_e, int nnz)
{
    int i = blockIdx.x * 256 + threadIdx.x;
    if (i < nnz) {
        atomicAdd(&cnt_v[vertex[i]], 1);
        atomicAdd(&cnt_e[edges[i]], 1);
    }
}

// ---------- single-block exclusive scan: off[0..n] from cnt[0..n) ----------
__global__ __launch_bounds__(256)
void scan_k(const int* __restrict__ cnt, int* __restrict__ off, int n)
{
    __shared__ int s[256];
    __shared__ int carry;
    if (threadIdx.x == 0) carry = 0;
    __syncthreads();
    for (int base = 0; base < n; base += 1024) {
        int v[4], sum = 0;
        int idx = base + threadIdx.x * 4;
        #pragma unroll
        for (int j = 0; j < 4; ++j) { v[j] = (idx + j < n) ? cnt[idx + j] : 0; sum += v[j]; }
        s[threadIdx.x] = sum;
        __syncthreads();
        #pragma unroll
        for (int d = 1; d < 256; d <<= 1) {
            int t = (threadIdx.x >= d) ? s[threadIdx.x - d] : 0;
            __syncthreads();
            s[threadIdx.x] += t;
            __syncthreads();
        }
        int excl = carry + s[threadIdx.x] - sum;
        #pragma unroll
        for (int j = 0; j < 4; ++j) {
            if (idx + j < n) off[idx + j] = excl;
            excl += v[j];
        }
        int total = s[255];
        __syncthreads();
        if (threadIdx.x == 0) carry += total;
        __syncthreads();
    }
    if (threadIdx.x == 0) off[n] = carry;
}

// ---------- copy two int arrays (cursor init) ----------
__global__ __launch_bounds__(256)
void copy2_k(const int* __restrict__ s1, int* __restrict__ d1, int n1,
             const int* __restrict__ s2, int* __restrict__ d2, int n2)
{
    int i = blockIdx.x * 256 + threadIdx.x;
    int stride = gridDim.x * 256;
    for (int j = i; j < n1; j += stride) d1[j] = s1[j];
    for (int j = i; j < n2; j += stride) d2[j] = s2[j];
}

// ---------- CSR adjacency fill ----------
__global__ __launch_bounds__(256)
void csr_fill_k(const int* __restrict__ vertex, const int* __restrict__ edges,
                int* __restrict__ cur_e, int* __restrict__ cur_v,
                int* __restrict__ adj_e, int* __restrict__ adj_v, int nnz)
{
    int i = blockIdx.x * 256 + threadIdx.x;
    if (i >= nnz) return;
    int v = vertex[i], e = edges[i];
    adj_e[atomicAdd(&cur_e[e], 1)] = v;   // edge e's member vertices
    adj_v[atomicAdd(&cur_v[v], 1)] = e;   // vertex v's member edges
}

// ---------- gather segment-sum: dst[seg] (+)= sum over adj rows of src ----------
template<bool ACCUM>
__global__ __launch_bounds__(256)
void gather_sum_k(const bf16* __restrict__ src, const int* __restrict__ adj,
                  const int* __restrict__ off, bf16* __restrict__ dst, int nseg)
{
    int seg = blockIdx.x * 4 + (threadIdx.x >> 6);
    if (seg >= nseg) return;
    int lane = threadIdx.x & 63;
    int s0 = off[seg], s1 = off[seg + 1];
    float4 acc = make_float4(0.f, 0.f, 0.f, 0.f);
    bf16* dp = dst + (size_t)seg * HD + lane * 4;
    if (ACCUM) acc = load4f(dp);
    for (int j = s0; j < s1; ++j) {
        int r = adj[j];
        float4 v = load4f(src + (size_t)r * HD + lane * 4);
        acc.x += v.x; acc.y += v.y; acc.z += v.z; acc.w += v.w;
    }
    store4(dp, acc);
}

// ---------- tiled GEMM: C = epi(A@B + bias), A may be 0.5*(A+A2) ----------
// EPI: 0 = none, 1 = relu, 2 = deg-scale: C = deg[row]*(acc + bias)
template<int EPI, bool HALF2, class TA, class TA2, class TC>
__global__ __launch_bounds__(256)
void gemm_k(const TA* __restrict__ Ag, const TA2* __restrict__ A2g,
            const float* __restrict__ Bg, const float* __restrict__ bias,
            const int* __restrict__ deg, TC* __restrict__ Cg,
            int M, int K, int Nc)
{
    __shared__ float As[BM][BK + 4];
    __shared__ float Bs[BK][BN];

    const int t  = threadIdx.x;
    const int tx = t & 15;
    const int ty = t >> 4;
    const int bm = blockIdx.x * BM;
    const int bn = blockIdx.y * BN;

    float acc[4][4] = {};

    for (int k0 = 0; k0 < K; k0 += BK) {
        #pragma unroll
        for (int L = 0; L < 2; ++L) {
            int idx = t + L * 256;
            int r   = idx >> 3;
            int kc  = (idx & 7) << 2;
            int row = bm + r;
            float4 v = make_float4(0.f, 0.f, 0.f, 0.f);
            if (row < M) {
                v = load4f(Ag + (size_t)row * K + k0 + kc);
                if (HALF2) {
                    float4 w = load4f(A2g + (size_t)row * K + k0 + kc);
                    v.x = 0.5f * (v.x + w.x); v.y = 0.5f * (v.y + w.y);
                    v.z = 0.5f * (v.z + w.z); v.w = 0.5f * (v.w + w.w);
                }
            }
            *reinterpret_cast<float4*>(&As[r][kc]) = v;
        }
        #pragma unroll
        for (int L = 0; L < 2; ++L) {
            int idx = t + L * 256;
            int kr  = idx >> 4;
            int nc  = (idx & 15) << 2;
            float4 v = *reinterpret_cast<const float4*>(Bg + (size_t)(k0 + kr) * Nc + bn + nc);
            *reinterpret_cast<float4*>(&Bs[kr][nc]) = v;
        }
        __syncthreads();

        #pragma unroll
        for (int k = 0; k < BK; k += 4) {
            float4 a[4], b[4];
            #pragma unroll
            for (int i = 0; i < 4; ++i)
                a[i] = *reinterpret_cast<const float4*>(&As[ty * 4 + i][k]);
            #pragma unroll
            for (int j = 0; j < 4; ++j)
                b[j] = *reinterpret_cast<const float4*>(&Bs[k + j][tx * 4]);
            #pragma unroll
            for (int j = 0; j < 4; ++j) {
                #pragma unroll
                for (int i = 0; i < 4; ++i) {
                    float av = (j == 0) ? a[i].x : (j == 1) ? a[i].y : (j == 2) ? a[i].z : a[i].w;
                    acc[i][0] += av * b[j].x;
                    acc[i][1] += av * b[j].y;
                    acc[i][2] += av * b[j].z;
                    acc[i][3] += av * b[j].w;
                }
            }
        }
        __syncthreads();
    }

    float4 bv = make_float4(0.f, 0.f, 0.f, 0.f);
    if (bias) bv = *reinterpret_cast<const float4*>(bias + bn + tx * 4);
    #pragma unroll
    for (int i = 0; i < 4; ++i) {
        int row = bm + ty * 4 + i;
        if (row >= M) continue;
        float4 o;
        o.x = acc[i][0] + bv.x; o.y = acc[i][1] + bv.y;
        o.z = acc[i][2] + bv.z; o.w = acc[i][3] + bv.w;
        if (EPI == 1) {
            o.x = fmaxf(o.x, 0.f); o.y = fmaxf(o.y, 0.f);
            o.z = fmaxf(o.z, 0.f); o.w = fmaxf(o.w, 0.f);
        } else if (EPI == 2) {
            float d = (float)deg[row];
            o.x *= d; o.y *= d; o.z *= d; o.w *= d;   // = d*(acc+bias)
        }
        store4(Cg + (size_t)row * Nc + bn + tx * 4, o);
    }
}

// ---------- classifier head: out[M,40] = H[M,256] @ W[256,40] + b ----------
__global__ __launch_bounds__(256)
void cls2_k(const bf16* __restrict__ Hm, const float* __restrict__ W,
            const float* __restrict__ bias, float* __restrict__ out, int M)
{
    __shared__ float ws_[HD][NCLS];
    for (int i = threadIdx.x; i < HD * NCLS; i += 256)
        ws_[i / NCLS][i % NCLS] = W[i];
    __syncthreads();
    int row  = blockIdx.x * 4 + (threadIdx.x >> 6);
    int lane = threadIdx.x & 63;
    if (row >= M || lane >= NCLS) return;
    const bf16* hr = Hm + (size_t)row * HD;
    float sum = bias[lane];
    #pragma unroll 8
    for (int k = 0; k < HD; ++k) sum += tofl(hr[k]) * ws_[k][lane];
    out[(size_t)row * NCLS + lane] = sum;
}

extern "C" void kernel_launch(void* const* d_in, const int* in_sizes, int n_in,
                              void* d_out, int out_size, void* d_ws, size_t ws_size,
                              hipStream_t stream)
{
    const float* x_in   = (const float*)d_in[0];
    const int*   vertex = (const int*)d_in[1];
    const int*   edges  = (const int*)d_in[2];
    const float* lin_w  = (const float*)d_in[3];
    const float* lin_b  = (const float*)d_in[4];
    const float* w1     = (const float*)d_in[5];
    const float* b1     = (const float*)d_in[6];
    const float* w2     = (const float*)d_in[7];   // [512,256]: rows 0..255 w2a, 256..511 w2b
    const float* b2     = (const float*)d_in[8];
    const float* w3     = (const float*)d_in[9];
    const float* b3     = (const float*)d_in[10];
    const float* cw1    = (const float*)d_in[11];
    const float* cb1    = (const float*)d_in[12];
    const float* cw2    = (const float*)d_in[13];
    const float* cb2    = (const float*)d_in[14];
    float* out = (float*)d_out;
    (void)in_sizes; (void)n_in; (void)out_size; (void)ws_size;

    char* ws = (char*)d_ws;
    const size_t nvhd = (size_t)NV * HD, nehd = (size_t)NE * HD;
    size_t off = 0;
    auto alloc = [&](size_t bytes) { char* p = ws + off; off += (bytes + 255) & ~(size_t)255; return p; };
    bf16* x0 = (bf16*)alloc(nvhd * 2);     // restart anchor
    bf16* xA = (bf16*)alloc(nvhd * 2);     // layer output
    bf16* E1 = (bf16*)alloc(nehd * 2);     // T1 -> Bm -> cls hidden
    bf16* E2 = (bf16*)alloc(nehd * 2);     // xe -> xv
    int* cnt_e = (int*)alloc(NE * 4);      // also: edge degree
    int* cnt_v = (int*)alloc(NV * 4);      // also: vertex degree (GEMM epilogue)
    int* off_e = (int*)alloc((NE + 1) * 4);
    int* off_v = (int*)alloc((NV + 1) * 4);
    int* cur_e = (int*)alloc(NE * 4);
    int* cur_v = (int*)alloc(NV * 4);
    int* adj_e = (int*)alloc((size_t)NNZC * 4);
    int* adj_v = (int*)alloc((size_t)NNZC * 4);

    dim3 blk(256);
    dim3 gin((NV + BM - 1) / BM, HD / BN);   // 782 x 4
    dim3 ge((NE + BM - 1) / BM, HD / BN);    // 1250 x 4

    // ---- CSR build ----
    fill0_k<<<128, blk, 0, stream>>>((unsigned int*)cnt_e, NE);
    fill0_k<<<128, blk, 0, stream>>>((unsigned int*)cnt_v, NV);
    hist_k<<<(NNZC + 255) / 256, blk, 0, stream>>>(vertex, edges, cnt_v, cnt_e, NNZC);
    scan_k<<<1, blk, 0, stream>>>(cnt_e, off_e, NE);
    scan_k<<<1, blk, 0, stream>>>(cnt_v, off_v, NV);
    copy2_k<<<128, blk, 0, stream>>>(off_e, cur_e, NE, off_v, cur_v, NV);
    csr_fill_k<<<(NNZC + 255) / 256, blk, 0, stream>>>(vertex, edges, cur_e, cur_v, adj_e, adj_v, NNZC);

    // ---- input projection: x0 = relu(x_in @ lin_w + lin_b) ----
    gemm_k<1, false, float, float, bf16><<<gin, blk, 0, stream>>>(
        x_in, nullptr, lin_w, lin_b, nullptr, x0, NV, FINC, HD);

    const bf16* cur = x0;
    for (int layer = 0; layer < 2; ++layer) {
        // E1(T1) = cur @ w1 + b1
        gemm_k<0, false, bf16, bf16, bf16><<<gin, blk, 0, stream>>>(
            cur, nullptr, w1, b1, nullptr, E1, NV, HD, HD);
        // E2(xe) = segment_sum(T1[vertex], edges)  [gather, no atomics]
        gather_sum_k<false><<<(NE + 3) / 4, blk, 0, stream>>>(E1, adj_e, off_e, E2, NE);
        // E1(Bm) = xe @ w2b
        gemm_k<0, false, bf16, bf16, bf16><<<ge, blk, 0, stream>>>(
            E2, nullptr, w2 + HD * HD, nullptr, nullptr, E1, NE, HD, HD);
        // E2(xv) = deg_v * (cur @ w2a + b2)
        gemm_k<2, false, bf16, bf16, bf16><<<gin, blk, 0, stream>>>(
            cur, nullptr, w2, b2, cnt_v, E2, NV, HD, HD);
        // xv += segment_sum(Bm[edges], vertex)  [gather, accumulate]
        gather_sum_k<true><<<(NV + 3) / 4, blk, 0, stream>>>(E1, adj_v, off_v, E2, NV);
        // xA = relu((0.5*xv + 0.5*x0) @ w3 + b3)
        gemm_k<1, true, bf16, bf16, bf16><<<gin, blk, 0, stream>>>(
            E2, x0, w3, b3, nullptr, xA, NV, HD, HD);
        cur = xA;
    }

    // ---- classifier ----
    gemm_k<1, false, bf16, bf16, bf16><<<gin, blk, 0, stream>>>(
        xA, nullptr, cw1, cb1, nullptr, E1, NV, HD, HD);
    cls2_k<<<(NV + 3) / 4, blk, 0, stream>>>(E1, cw2, cb2, out, NV);
}

// Round 4
// 880.731 us; speedup vs baseline: 7.5837x; 1.9645x over previous
//
#include <hip/hip_runtime.h>
#include <hip/hip_bf16.h>
#include <cstdint>
#include <cstddef>

#define HD   256
#define NV   50000
#define NE   80000
#define NNZC 400000
#define FINC 512
#define NCLS 40

using bf16 = __hip_bfloat16;

typedef short bf16x8v __attribute__((ext_vector_type(8)));
typedef float f32x4   __attribute__((ext_vector_type(4)));

// ---------- dtype helpers ----------
__device__ __forceinline__ float b2f(unsigned short u) {
    union { unsigned int i; float f; } c; c.i = ((unsigned int)u) << 16; return c.f;
}
__device__ __forceinline__ unsigned short f2b(float f) {
    union { float f; unsigned int i; } c; c.f = f;
    return (unsigned short)((c.i + 0x7FFFu + ((c.i >> 16) & 1u)) >> 16);
}
__device__ __forceinline__ float4 load4f(const bf16* p) {
    ushort4 u = *reinterpret_cast<const ushort4*>(p);
    return make_float4(b2f(u.x), b2f(u.y), b2f(u.z), b2f(u.w));
}
__device__ __forceinline__ void store4(bf16* p, float4 v) {
    ushort4 u; u.x = f2b(v.x); u.y = f2b(v.y); u.z = f2b(v.z); u.w = f2b(v.w);
    *reinterpret_cast<ushort4*>(p) = u;
}

// ---------- async global->LDS, 16B per lane ----------
__device__ __forceinline__ void gl_lds16(const bf16* g, short* l) {
    __builtin_amdgcn_global_load_lds(
        (const __attribute__((address_space(1))) unsigned int*)g,
        (__attribute__((address_space(3))) unsigned int*)l,
        16, 0, 0);
}

// ---------- capture-safe zero fill ----------
__global__ __launch_bounds__(256)
void fill0_k(unsigned int* __restrict__ p, long long n)
{
    long long i = (long long)blockIdx.x * 256 + threadIdx.x;
    long long stride = (long long)gridDim.x * 256;
    for (; i < n; i += stride) p[i] = 0u;
}

// ---------- combined histogram ----------
__global__ __launch_bounds__(256)
void hist_k(const int* __restrict__ vertex, const int* __restrict__ edges,
            int* __restrict__ cnt_v, int* __restrict__ cnt_e, int nnz)
{
    int i = blockIdx.x * 256 + threadIdx.x;
    if (i < nnz) {
        atomicAdd(&cnt_v[vertex[i]], 1);
        atomicAdd(&cnt_e[edges[i]], 1);
    }
}

// ---------- single-block exclusive scan ----------
__global__ __launch_bounds__(256)
void scan_k(const int* __restrict__ cnt, int* __restrict__ off, int n)
{
    __shared__ int s[256];
    __shared__ int carry;
    if (threadIdx.x == 0) carry = 0;
    __syncthreads();
    for (int base = 0; base < n; base += 1024) {
        int v[4], sum = 0;
        int idx = base + threadIdx.x * 4;
        #pragma unroll
        for (int j = 0; j < 4; ++j) { v[j] = (idx + j < n) ? cnt[idx + j] : 0; sum += v[j]; }
        s[threadIdx.x] = sum;
        __syncthreads();
        #pragma unroll
        for (int d = 1; d < 256; d <<= 1) {
            int t = (threadIdx.x >= d) ? s[threadIdx.x - d] : 0;
            __syncthreads();
            s[threadIdx.x] += t;
            __syncthreads();
        }
        int excl = carry + s[threadIdx.x] - sum;
        #pragma unroll
        for (int j = 0; j < 4; ++j) {
            if (idx + j < n) off[idx + j] = excl;
            excl += v[j];
        }
        int total = s[255];
        __syncthreads();
        if (threadIdx.x == 0) carry += total;
        __syncthreads();
    }
    if (threadIdx.x == 0) off[n] = carry;
}

// ---------- cursor init ----------
__global__ __launch_bounds__(256)
void copy2_k(const int* __restrict__ s1, int* __restrict__ d1, int n1,
             const int* __restrict__ s2, int* __restrict__ d2, int n2)
{
    int i = blockIdx.x * 256 + threadIdx.x;
    int stride = gridDim.x * 256;
    for (int j = i; j < n1; j += stride) d1[j] = s1[j];
    for (int j = i; j < n2; j += stride) d2[j] = s2[j];
}

// ---------- CSR adjacency fill ----------
__global__ __launch_bounds__(256)
void csr_fill_k(const int* __restrict__ vertex, const int* __restrict__ edges,
                int* __restrict__ cur_e, int* __restrict__ cur_v,
                int* __restrict__ adj_e, int* __restrict__ adj_v, int nnz)
{
    int i = blockIdx.x * 256 + threadIdx.x;
    if (i >= nnz) return;
    int v = vertex[i], e = edges[i];
    adj_e[atomicAdd(&cur_e[e], 1)] = v;
    adj_v[atomicAdd(&cur_v[v], 1)] = e;
}

// ---------- weight prep: transpose to [N][K] + bf16 ----------
__global__ __launch_bounds__(256)
void prep_w_k(const float* __restrict__ lin_w, const float* __restrict__ w1,
              const float* __restrict__ w2, const float* __restrict__ w3,
              const float* __restrict__ cw1,
              unsigned short* __restrict__ lin_wt, unsigned short* __restrict__ w1t,
              unsigned short* __restrict__ w2at, unsigned short* __restrict__ w2bt,
              unsigned short* __restrict__ w3t, unsigned short* __restrict__ cw1t)
{
    int idx = blockIdx.x * 256 + threadIdx.x;          // 0 .. 458751
    if (idx < 131072) {                                // lin_wt [256][512]
        int n = idx >> 9, k = idx & 511;
        lin_wt[idx] = f2b(lin_w[k * 256 + n]);
        return;
    }
    idx -= 131072;
    int mat = idx >> 16;                               // 65536 each
    int r = idx & 65535;
    int n = r >> 8, k = r & 255;
    float v; unsigned short* dst;
    switch (mat) {
        case 0:  v = w1[k * 256 + n];         dst = w1t;  break;
        case 1:  v = w2[k * 256 + n];         dst = w2at; break;
        case 2:  v = w2[(256 + k) * 256 + n]; dst = w2bt; break;
        case 3:  v = w3[k * 256 + n];         dst = w3t;  break;
        default: v = cw1[k * 256 + n];        dst = cw1t; break;
    }
    dst[r] = f2b(v);
}

// ---------- x_in f32 -> bf16 ----------
__global__ __launch_bounds__(256)
void xcvt_k(const float* __restrict__ x, unsigned short* __restrict__ o, long long n4)
{
    long long i = (long long)blockIdx.x * 256 + threadIdx.x;
    long long stride = (long long)gridDim.x * 256;
    for (; i < n4; i += stride) {
        float4 v = reinterpret_cast<const float4*>(x)[i];
        ushort4 u; u.x = f2b(v.x); u.y = f2b(v.y); u.z = f2b(v.z); u.w = f2b(v.w);
        reinterpret_cast<ushort4*>(o)[i] = u;
    }
}

// ---------- MFMA bf16 GEMM: C[M,Nc] = epi(A[M,K] @ Bt[Nc,K]^T + bias) ----------
// EPI: 0 none, 1 relu, 2 deg[row]*(acc+bias). Tile 128x128, BK=64, 4 waves.
template<int EPI>
__global__ __launch_bounds__(256)
void mgemm_k(const bf16* __restrict__ Ag, const bf16* __restrict__ Bt,
             const float* __restrict__ bias, const int* __restrict__ deg,
             bf16* __restrict__ Cg, int M, int K, int Nc)
{
    __shared__ __align__(16) short As[128 * 64];
    __shared__ __align__(16) short Bs[128 * 64];

    const int t  = threadIdx.x;
    const int wv = t >> 6, l = t & 63;
    const int wr = wv >> 1, wc = wv & 1;
    const int bm = blockIdx.x * 128;
    const int bn = blockIdx.y * 128;

    f32x4 acc[4][4];
    #pragma unroll
    for (int m = 0; m < 4; ++m)
        #pragma unroll
        for (int n = 0; n < 4; ++n)
            acc[m][n] = (f32x4){0.f, 0.f, 0.f, 0.f};

    const int arow8 = l >> 3;          // row within 8-row chunk
    const int acol  = (l & 7) * 8;     // bf16 col within BK=64

    for (int k0 = 0; k0 < K; k0 += 64) {
        #pragma unroll
        for (int i = 0; i < 4; ++i) {
            int c = wv * 4 + i;                 // chunk 0..15 (8 rows each)
            int row = c * 8 + arow8;
            int ga = bm + row; if (ga >= M) ga = M - 1;   // clamp: garbage rows masked at store
            gl_lds16(Ag + (size_t)ga * K + k0 + acol, As + c * 512);
            gl_lds16(Bt + (size_t)(bn + row) * K + k0 + acol, Bs + c * 512);
        }
        __syncthreads();   // drains vmcnt -> LDS visible

        #pragma unroll
        for (int ks = 0; ks < 2; ++ks) {
            bf16x8v a[4], b[4];
            const int kb = ks * 64 + (l >> 4) * 16;      // byte offset within 128B row
            #pragma unroll
            for (int m = 0; m < 4; ++m) {
                int r = wr * 64 + m * 16 + (l & 15);
                a[m] = *reinterpret_cast<const bf16x8v*>((const char*)As + r * 128 + kb);
            }
            #pragma unroll
            for (int n = 0; n < 4; ++n) {
                int r = wc * 64 + n * 16 + (l & 15);
                b[n] = *reinterpret_cast<const bf16x8v*>((const char*)Bs + r * 128 + kb);
            }
            #pragma unroll
            for (int m = 0; m < 4; ++m)
                #pragma unroll
                for (int n = 0; n < 4; ++n)
                    acc[m][n] = __builtin_amdgcn_mfma_f32_16x16x32_bf16(a[m], b[n], acc[m][n], 0, 0, 0);
        }
        __syncthreads();
    }

    // epilogue: C row = (lane>>4)*4 + reg, col = lane&15  [m89/m91 layout]
    float bv[4];
    #pragma unroll
    for (int n = 0; n < 4; ++n)
        bv[n] = bias ? bias[bn + wc * 64 + n * 16 + (l & 15)] : 0.f;
    #pragma unroll
    for (int m = 0; m < 4; ++m) {
        #pragma unroll
        for (int i = 0; i < 4; ++i) {
            int row = bm + wr * 64 + m * 16 + (l >> 4) * 4 + i;
            if (row >= M) continue;
            float d = (EPI == 2) ? (float)deg[row] : 1.f;
            size_t base = (size_t)row * Nc + bn + wc * 64 + (l & 15);
            #pragma unroll
            for (int n = 0; n < 4; ++n) {
                float v = acc[m][n][i] + bv[n];
                if (EPI == 1) v = fmaxf(v, 0.f);
                if (EPI == 2) v *= d;
                reinterpret_cast<unsigned short*>(Cg)[base + n * 16] = f2b(v);
            }
        }
    }
}

// ---------- gather segment-sum ----------
// MODE 0: dst[seg] = sum(src rows)            (xe)
// MODE 1: dst[seg] = 0.5*(dst[seg] + sum) + 0.5*x0[seg]   (xv + restart fusion)
template<int MODE>
__global__ __launch_bounds__(256)
void gather_sum_k(const bf16* __restrict__ src, const int* __restrict__ adj,
                  const int* __restrict__ off, const bf16* __restrict__ x0,
                  bf16* __restrict__ dst, int nseg)
{
    int seg = blockIdx.x * 4 + (threadIdx.x >> 6);
    if (seg >= nseg) return;
    int lane = threadIdx.x & 63;
    int s0 = off[seg], s1 = off[seg + 1];
    float4 acc = make_float4(0.f, 0.f, 0.f, 0.f);
    bf16* dp = dst + (size_t)seg * HD + lane * 4;
    if (MODE == 1) acc = load4f(dp);
    for (int j = s0; j < s1; ++j) {
        int r = adj[j];
        float4 v = load4f(src + (size_t)r * HD + lane * 4);
        acc.x += v.x; acc.y += v.y; acc.z += v.z; acc.w += v.w;
    }
    if (MODE == 1) {
        float4 x = load4f(x0 + (size_t)seg * HD + lane * 4);
        acc.x = 0.5f * acc.x + 0.5f * x.x;
        acc.y = 0.5f * acc.y + 0.5f * x.y;
        acc.z = 0.5f * acc.z + 0.5f * x.z;
        acc.w = 0.5f * acc.w + 0.5f * x.w;
    }
    store4(dp, acc);
}

// ---------- classifier head ----------
__global__ __launch_bounds__(256)
void cls2_k(const bf16* __restrict__ Hm, const float* __restrict__ W,
            const float* __restrict__ bias, float* __restrict__ out, int M)
{
    __shared__ float ws_[HD][NCLS];
    for (int i = threadIdx.x; i < HD * NCLS; i += 256)
        ws_[i / NCLS][i % NCLS] = W[i];
    __syncthreads();
    int row  = blockIdx.x * 4 + (threadIdx.x >> 6);
    int lane = threadIdx.x & 63;
    if (row >= M || lane >= NCLS) return;
    const bf16* hr = Hm + (size_t)row * HD;
    float sum = bias[lane];
    #pragma unroll 8
    for (int k = 0; k < HD; ++k) sum += __bfloat162float(hr[k]) * ws_[k][lane];
    out[(size_t)row * NCLS + lane] = sum;
}

extern "C" void kernel_launch(void* const* d_in, const int* in_sizes, int n_in,
                              void* d_out, int out_size, void* d_ws, size_t ws_size,
                              hipStream_t stream)
{
    const float* x_in   = (const float*)d_in[0];
    const int*   vertex = (const int*)d_in[1];
    const int*   edges  = (const int*)d_in[2];
    const float* lin_w  = (const float*)d_in[3];
    const float* lin_b  = (const float*)d_in[4];
    const float* w1     = (const float*)d_in[5];
    const float* b1     = (const float*)d_in[6];
    const float* w2     = (const float*)d_in[7];
    const float* b2     = (const float*)d_in[8];
    const float* w3     = (const float*)d_in[9];
    const float* b3     = (const float*)d_in[10];
    const float* cw1    = (const float*)d_in[11];
    const float* cb1    = (const float*)d_in[12];
    const float* cw2    = (const float*)d_in[13];
    const float* cb2    = (const float*)d_in[14];
    float* out = (float*)d_out;
    (void)in_sizes; (void)n_in; (void)out_size; (void)ws_size;

    char* ws = (char*)d_ws;
    const size_t nvhd = (size_t)NV * HD, nehd = (size_t)NE * HD;
    size_t off = 0;
    auto alloc = [&](size_t bytes) { char* p = ws + off; off += (bytes + 255) & ~(size_t)255; return p; };
    bf16* x0 = (bf16*)alloc(nvhd * 2);          // restart anchor
    bf16* xA = (bf16*)alloc(nvhd * 2);          // layer output
    bf16* E1 = (bf16*)alloc(nehd * 2);          // T1 -> Bm -> cls hidden
    bf16* E2 = (bf16*)alloc(nehd * 2);          // xe -> xv
    bf16* xf = (bf16*)alloc((size_t)NV * FINC * 2);   // x_in bf16
    unsigned short* lin_wt = (unsigned short*)alloc(256 * 512 * 2);
    unsigned short* w1t    = (unsigned short*)alloc(256 * 256 * 2);
    unsigned short* w2at   = (unsigned short*)alloc(256 * 256 * 2);
    unsigned short* w2bt   = (unsigned short*)alloc(256 * 256 * 2);
    unsigned short* w3t    = (unsigned short*)alloc(256 * 256 * 2);
    unsigned short* cw1t   = (unsigned short*)alloc(256 * 256 * 2);
    int* cnt_e = (int*)alloc(NE * 4);
    int* cnt_v = (int*)alloc(NV * 4);           // vertex degree (GEMM epilogue)
    int* off_e = (int*)alloc((NE + 1) * 4);
    int* off_v = (int*)alloc((NV + 1) * 4);
    int* cur_e = (int*)alloc(NE * 4);
    int* cur_v = (int*)alloc(NV * 4);
    int* adj_e = (int*)alloc((size_t)NNZC * 4);
    int* adj_v = (int*)alloc((size_t)NNZC * 4);

    dim3 blk(256);
    dim3 gv((NV + 127) / 128, 2);    // 391 x 2
    dim3 ge((NE + 127) / 128, 2);    // 625 x 2

    // ---- CSR build ----
    fill0_k<<<128, blk, 0, stream>>>((unsigned int*)cnt_e, NE);
    fill0_k<<<128, blk, 0, stream>>>((unsigned int*)cnt_v, NV);
    hist_k<<<(NNZC + 255) / 256, blk, 0, stream>>>(vertex, edges, cnt_v, cnt_e, NNZC);
    scan_k<<<1, blk, 0, stream>>>(cnt_e, off_e, NE);
    scan_k<<<1, blk, 0, stream>>>(cnt_v, off_v, NV);
    copy2_k<<<128, blk, 0, stream>>>(off_e, cur_e, NE, off_v, cur_v, NV);
    csr_fill_k<<<(NNZC + 255) / 256, blk, 0, stream>>>(vertex, edges, cur_e, cur_v, adj_e, adj_v, NNZC);

    // ---- dtype prep ----
    prep_w_k<<<1792, blk, 0, stream>>>(lin_w, w1, w2, w3, cw1,
                                       lin_wt, w1t, w2at, w2bt, w3t, cw1t);
    xcvt_k<<<2048, blk, 0, stream>>>(x_in, (unsigned short*)xf, (long long)NV * FINC / 4);

    // ---- x0 = relu(xf @ lin_w + lin_b) ----
    mgemm_k<1><<<gv, blk, 0, stream>>>(xf, (const bf16*)lin_wt, lin_b, nullptr, x0, NV, FINC, HD);

    const bf16* cur = x0;
    for (int layer = 0; layer < 2; ++layer) {
        // E1(T1) = cur @ w1 + b1
        mgemm_k<0><<<gv, blk, 0, stream>>>(cur, (const bf16*)w1t, b1, nullptr, E1, NV, HD, HD);
        // E2(xe) = segment_sum(T1[vertex], edges)
        gather_sum_k<0><<<(NE + 3) / 4, blk, 0, stream>>>(E1, adj_e, off_e, nullptr, E2, NE);
        // E1(Bm) = xe @ w2b
        mgemm_k<0><<<ge, blk, 0, stream>>>(E2, (const bf16*)w2bt, nullptr, nullptr, E1, NE, HD, HD);
        // E2(xv) = deg_v * (cur @ w2a + b2)
        mgemm_k<2><<<gv, blk, 0, stream>>>(cur, (const bf16*)w2at, b2, cnt_v, E2, NV, HD, HD);
        // E2 = 0.5*(xv + sum Bm[edges]) + 0.5*x0   (restart fused)
        gather_sum_k<1><<<(NV + 3) / 4, blk, 0, stream>>>(E1, adj_v, off_v, x0, E2, NV);
        // xA = relu(E2 @ w3 + b3)
        mgemm_k<1><<<gv, blk, 0, stream>>>(E2, (const bf16*)w3t, b3, nullptr, xA, NV, HD, HD);
        cur = xA;
    }

    // ---- classifier ----
    mgemm_k<1><<<gv, blk, 0, stream>>>(xA, (const bf16*)cw1t, cb1, nullptr, E1, NV, HD, HD);
    cls2_k<<<(NV + 3) / 4, blk, 0, stream>>>(E1, cw2, cb2, out, NV);
}

// Round 5
// 600.143 us; speedup vs baseline: 11.1294x; 1.4675x over previous
//
#include <hip/hip_runtime.h>
#include <hip/hip_bf16.h>
#include <cstdint>
#include <cstddef>

#define HD   256
#define NV   50000
#define NE   80000
#define NNZC 400000
#define FINC 512
#define NCLS 40

using bf16 = __hip_bfloat16;

typedef short bf16x8v __attribute__((ext_vector_type(8)));
typedef float f32x4   __attribute__((ext_vector_type(4)));

// ---------- dtype helpers ----------
__device__ __forceinline__ float b2f(unsigned short u) {
    union { unsigned int i; float f; } c; c.i = ((unsigned int)u) << 16; return c.f;
}
__device__ __forceinline__ unsigned short f2b(float f) {
    union { float f; unsigned int i; } c; c.f = f;
    return (unsigned short)((c.i + 0x7FFFu + ((c.i >> 16) & 1u)) >> 16);
}
__device__ __forceinline__ float4 load4f(const bf16* p) {
    ushort4 u = *reinterpret_cast<const ushort4*>(p);
    return make_float4(b2f(u.x), b2f(u.y), b2f(u.z), b2f(u.w));
}
__device__ __forceinline__ void store4(bf16* p, float4 v) {
    ushort4 u; u.x = f2b(v.x); u.y = f2b(v.y); u.z = f2b(v.z); u.w = f2b(v.w);
    *reinterpret_cast<ushort4*>(p) = u;
}

// ---------- async global->LDS, 16B per lane ----------
__device__ __forceinline__ void gl_lds16(const bf16* g, short* l) {
    __builtin_amdgcn_global_load_lds(
        (const __attribute__((address_space(1))) unsigned int*)g,
        (__attribute__((address_space(3))) unsigned int*)l,
        16, 0, 0);
}

// ---------- capture-safe zero fill ----------
__global__ __launch_bounds__(256)
void fill0_k(unsigned int* __restrict__ p, long long n)
{
    long long i = (long long)blockIdx.x * 256 + threadIdx.x;
    long long stride = (long long)gridDim.x * 256;
    for (; i < n; i += stride) p[i] = 0u;
}

// ---------- combined histogram ----------
__global__ __launch_bounds__(256)
void hist_k(const int* __restrict__ vertex, const int* __restrict__ edges,
            int* __restrict__ cnt_v, int* __restrict__ cnt_e, int nnz)
{
    int i = blockIdx.x * 256 + threadIdx.x;
    if (i < nnz) {
        atomicAdd(&cnt_v[vertex[i]], 1);
        atomicAdd(&cnt_e[edges[i]], 1);
    }
}

// ---------- 3-phase multi-block exclusive scan ----------
__global__ __launch_bounds__(256)
void scan_part_k(const int* __restrict__ cnt, int* __restrict__ off,
                 int* __restrict__ part, int n)
{
    __shared__ int s[256];
    int base = blockIdx.x * 1024;
    int idx = base + threadIdx.x * 4;
    int v[4], sum = 0;
    #pragma unroll
    for (int j = 0; j < 4; ++j) { v[j] = (idx + j < n) ? cnt[idx + j] : 0; sum += v[j]; }
    s[threadIdx.x] = sum;
    __syncthreads();
    #pragma unroll
    for (int d = 1; d < 256; d <<= 1) {
        int t = (threadIdx.x >= d) ? s[threadIdx.x - d] : 0;
        __syncthreads();
        s[threadIdx.x] += t;
        __syncthreads();
    }
    int excl = s[threadIdx.x] - sum;
    #pragma unroll
    for (int j = 0; j < 4; ++j) {
        if (idx + j < n) off[idx + j] = excl;
        excl += v[j];
    }
    if (threadIdx.x == 255) part[blockIdx.x] = s[255];
}

__global__ __launch_bounds__(256)
void scan_top_k(int* __restrict__ part, int* __restrict__ off_end, int nchunks)
{
    __shared__ int s[256];
    int v = (threadIdx.x < nchunks) ? part[threadIdx.x] : 0;
    s[threadIdx.x] = v;
    __syncthreads();
    #pragma unroll
    for (int d = 1; d < 256; d <<= 1) {
        int t = (threadIdx.x >= d) ? s[threadIdx.x - d] : 0;
        __syncthreads();
        s[threadIdx.x] += t;
        __syncthreads();
    }
    if (threadIdx.x < nchunks) part[threadIdx.x] = s[threadIdx.x] - v;
    if (threadIdx.x == 255) *off_end = s[255];
}

__global__ __launch_bounds__(256)
void scan_add_k(int* __restrict__ off, const int* __restrict__ part, int n)
{
    int i = blockIdx.x * 256 + threadIdx.x;
    if (i < n) off[i] += part[i >> 10];
}

// ---------- cursor init ----------
__global__ __launch_bounds__(256)
void copy2_k(const int* __restrict__ s1, int* __restrict__ d1, int n1,
             const int* __restrict__ s2, int* __restrict__ d2, int n2)
{
    int i = blockIdx.x * 256 + threadIdx.x;
    int stride = gridDim.x * 256;
    for (int j = i; j < n1; j += stride) d1[j] = s1[j];
    for (int j = i; j < n2; j += stride) d2[j] = s2[j];
}

// ---------- CSR adjacency fill ----------
__global__ __launch_bounds__(256)
void csr_fill_k(const int* __restrict__ vertex, const int* __restrict__ edges,
                int* __restrict__ cur_e, int* __restrict__ cur_v,
                int* __restrict__ adj_e, int* __restrict__ adj_v, int nnz)
{
    int i = blockIdx.x * 256 + threadIdx.x;
    if (i >= nnz) return;
    int v = vertex[i], e = edges[i];
    adj_e[atomicAdd(&cur_e[e], 1)] = v;
    adj_v[atomicAdd(&cur_v[v], 1)] = e;
}

// ---------- weight prep ----------
// lin_wt [256][512] (B^T), w1t/w3t/cw1t [256][256] (B^T),
// w2a_nb/w2b_nb [256][256] row-major bf16 copies, cw2t [48][256] (B^T, zero-pad)
__global__ __launch_bounds__(256)
void prep_w_k(const float* __restrict__ lin_w, const float* __restrict__ w1,
              const float* __restrict__ w2, const float* __restrict__ w3,
              const float* __restrict__ cw1, const float* __restrict__ cw2,
              unsigned short* __restrict__ lin_wt, unsigned short* __restrict__ w1t,
              unsigned short* __restrict__ w2a_nb, unsigned short* __restrict__ w2b_nb,
              unsigned short* __restrict__ w3t, unsigned short* __restrict__ cw1t,
              unsigned short* __restrict__ cw2t)
{
    int idx = blockIdx.x * 256 + threadIdx.x;          // < 471040
    if (idx < 131072) { int n = idx >> 9, k = idx & 511; lin_wt[idx] = f2b(lin_w[k * 256 + n]); return; }
    idx -= 131072;
    if (idx < 65536) { int n = idx >> 8, k = idx & 255; w1t[idx] = f2b(w1[k * 256 + n]); return; }
    idx -= 65536;
    if (idx < 65536) { w2a_nb[idx] = f2b(w2[idx]); return; }
    idx -= 65536;
    if (idx < 65536) { w2b_nb[idx] = f2b(w2[65536 + idx]); return; }
    idx -= 65536;
    if (idx < 65536) { int n = idx >> 8, k = idx & 255; w3t[idx] = f2b(w3[k * 256 + n]); return; }
    idx -= 65536;
    if (idx < 65536) { int n = idx >> 8, k = idx & 255; cw1t[idx] = f2b(cw1[k * 256 + n]); return; }
    idx -= 65536;
    { int n = idx >> 8, k = idx & 255; cw2t[idx] = f2b((n < NCLS) ? cw2[k * NCLS + n] : 0.f); }
}

// ---------- b2w3[n] = sum_k b2[k]*w3[k][n] ----------
__global__ __launch_bounds__(256)
void b2w3_k(const float* __restrict__ b2, const float* __restrict__ w3,
            float* __restrict__ o)
{
    int n = threadIdx.x;
    float s = 0.f;
    for (int k = 0; k < 256; ++k) s += b2[k] * w3[k * 256 + n];
    o[n] = s;
}

// ---------- x_in f32 -> bf16 ----------
__global__ __launch_bounds__(256)
void xcvt_k(const float* __restrict__ x, unsigned short* __restrict__ o, long long n4)
{
    long long i = (long long)blockIdx.x * 256 + threadIdx.x;
    long long stride = (long long)gridDim.x * 256;
    for (; i < n4; i += stride) {
        float4 v = reinterpret_cast<const float4*>(x)[i];
        ushort4 u; u.x = f2b(v.x); u.y = f2b(v.y); u.z = f2b(v.z); u.w = f2b(v.w);
        reinterpret_cast<ushort4*>(o)[i] = u;
    }
}

// ---------- MFMA bf16 GEMM: 128x128 tile, BK=64, 4 waves ----------
// EPI 0: C = A@Bt^T (+bias)
// EPI 1: C = relu(A@Bt^T + bias)
// EPI 3: dual split (Nc=512): cols<256 -> Cg (+bias), cols>=256 -> Cg2 (+bias2)
// EPI 4: C = relu(0.5*(deg[row]*(S+b2w3) + acc) + 0.5*z0 + bias)
template<int EPI>
__global__ __launch_bounds__(256)
void mgemm_k(const bf16* __restrict__ Ag, const bf16* __restrict__ Bt,
             const float* __restrict__ bias, const float* __restrict__ bias2,
             const int* __restrict__ deg,
             const bf16* __restrict__ Sb, const bf16* __restrict__ z0b,
             const float* __restrict__ b2w3v,
             bf16* __restrict__ Cg, bf16* __restrict__ Cg2,
             int M, int K, int Nc)
{
    __shared__ __align__(16) short As[128 * 64];
    __shared__ __align__(16) short Bs[128 * 64];

    const int t  = threadIdx.x;
    const int wv = t >> 6, l = t & 63;
    const int wr = wv >> 1, wc = wv & 1;
    const int bm = blockIdx.x * 128;
    const int bn = blockIdx.y * 128;
    const int l15 = l & 15;

    f32x4 acc[4][4];
    #pragma unroll
    for (int m = 0; m < 4; ++m)
        #pragma unroll
        for (int n = 0; n < 4; ++n)
            acc[m][n] = (f32x4){0.f, 0.f, 0.f, 0.f};

    const int arow8 = l >> 3;
    const int acol  = (l & 7) * 8;

    for (int k0 = 0; k0 < K; k0 += 64) {
        #pragma unroll
        for (int i = 0; i < 4; ++i) {
            int c = wv * 4 + i;
            int row = c * 8 + arow8;
            int ga = bm + row; if (ga >= M) ga = M - 1;
            gl_lds16(Ag + (size_t)ga * K + k0 + acol, As + c * 512);
            gl_lds16(Bt + (size_t)(bn + row) * K + k0 + acol, Bs + c * 512);
        }
        __syncthreads();

        #pragma unroll
        for (int ks = 0; ks < 2; ++ks) {
            bf16x8v a[4], b[4];
            const int kb = ks * 64 + (l >> 4) * 16;
            #pragma unroll
            for (int m = 0; m < 4; ++m) {
                int r = wr * 64 + m * 16 + l15;
                a[m] = *reinterpret_cast<const bf16x8v*>((const char*)As + r * 128 + kb);
            }
            #pragma unroll
            for (int n = 0; n < 4; ++n) {
                int r = wc * 64 + n * 16 + l15;
                b[n] = *reinterpret_cast<const bf16x8v*>((const char*)Bs + r * 128 + kb);
            }
            #pragma unroll
            for (int m = 0; m < 4; ++m)
                #pragma unroll
                for (int n = 0; n < 4; ++n)
                    acc[m][n] = __builtin_amdgcn_mfma_f32_16x16x32_bf16(a[m], b[n], acc[m][n], 0, 0, 0);
        }
        __syncthreads();
    }

    if (EPI == 3) {
        bool second = (bn >= 256);
        bf16* CC = second ? Cg2 : Cg;
        const float* bb = second ? bias2 : bias;
        int cb = bn - (second ? 256 : 0);
        float bv[4];
        #pragma unroll
        for (int n = 0; n < 4; ++n)
            bv[n] = bb ? bb[cb + wc * 64 + n * 16 + l15] : 0.f;
        #pragma unroll
        for (int m = 0; m < 4; ++m) {
            #pragma unroll
            for (int i = 0; i < 4; ++i) {
                int row = bm + wr * 64 + m * 16 + (l >> 4) * 4 + i;
                if (row >= M) continue;
                size_t base = (size_t)row * 256 + cb + wc * 64 + l15;
                #pragma unroll
                for (int n = 0; n < 4; ++n)
                    reinterpret_cast<unsigned short*>(CC)[base + n * 16] = f2b(acc[m][n][i] + bv[n]);
            }
        }
    } else if (EPI == 4) {
        float bv[4], bw[4];
        #pragma unroll
        for (int n = 0; n < 4; ++n) {
            int col = bn + wc * 64 + n * 16 + l15;
            bv[n] = bias[col];
            bw[n] = b2w3v[col];
        }
        #pragma unroll
        for (int m = 0; m < 4; ++m) {
            #pragma unroll
            for (int i = 0; i < 4; ++i) {
                int row = bm + wr * 64 + m * 16 + (l >> 4) * 4 + i;
                if (row >= M) continue;
                float d = (float)deg[row];
                size_t base = (size_t)row * Nc + bn + wc * 64 + l15;
                #pragma unroll
                for (int n = 0; n < 4; ++n) {
                    size_t idx = base + (size_t)n * 16;
                    float sv = b2f(reinterpret_cast<const unsigned short*>(Sb)[idx]);
                    float zv = b2f(reinterpret_cast<const unsigned short*>(z0b)[idx]);
                    float v = 0.5f * (d * (sv + bw[n]) + acc[m][n][i]) + 0.5f * zv + bv[n];
                    v = fmaxf(v, 0.f);
                    reinterpret_cast<unsigned short*>(Cg)[idx] = f2b(v);
                }
            }
        }
    } else {
        float bv[4];
        #pragma unroll
        for (int n = 0; n < 4; ++n)
            bv[n] = bias ? bias[bn + wc * 64 + n * 16 + l15] : 0.f;
        #pragma unroll
        for (int m = 0; m < 4; ++m) {
            #pragma unroll
            for (int i = 0; i < 4; ++i) {
                int row = bm + wr * 64 + m * 16 + (l >> 4) * 4 + i;
                if (row >= M) continue;
                size_t base = (size_t)row * Nc + bn + wc * 64 + l15;
                #pragma unroll
                for (int n = 0; n < 4; ++n) {
                    float v = acc[m][n][i] + bv[n];
                    if (EPI == 1) v = fmaxf(v, 0.f);
                    reinterpret_cast<unsigned short*>(Cg)[base + n * 16] = f2b(v);
                }
            }
        }
    }
}

// ---------- gather segment-sum: dst[seg] = sum_{j in seg} src[adj[j]] ----------
__global__ __launch_bounds__(256)
void gather_sum_k(const bf16* __restrict__ src, const int* __restrict__ adj,
                  const int* __restrict__ off, bf16* __restrict__ dst, int nseg)
{
    int seg = blockIdx.x * 4 + (threadIdx.x >> 6);
    if (seg >= nseg) return;
    int lane = threadIdx.x & 63;
    int s0 = off[seg], s1 = off[seg + 1];
    float4 acc = make_float4(0.f, 0.f, 0.f, 0.f);
    for (int j = s0; j < s1; ++j) {
        int r = adj[j];
        float4 v = load4f(src + (size_t)r * HD + lane * 4);
        acc.x += v.x; acc.y += v.y; acc.z += v.z; acc.w += v.w;
    }
    store4(dst + (size_t)seg * HD + lane * 4, acc);
}

// ---------- MFMA classifier: out[M,40] = H[M,256] @ cw2t[48,256]^T + cb2 ----------
__global__ __launch_bounds__(256)
void cls_mfma_k(const bf16* __restrict__ Hm, const bf16* __restrict__ Wt,
                const float* __restrict__ bias, float* __restrict__ out, int M)
{
    const int wv = threadIdx.x >> 6, l = threadIdx.x & 63;
    const int l15 = l & 15;
    const int r0 = blockIdx.x * 64 + wv * 16;
    f32x4 acc[3];
    #pragma unroll
    for (int n = 0; n < 3; ++n) acc[n] = (f32x4){0.f, 0.f, 0.f, 0.f};

    int arow = r0 + l15; if (arow >= M) arow = M - 1;
    const int ko = (l >> 4) * 8;
    for (int kk = 0; kk < HD; kk += 32) {
        bf16x8v a = *reinterpret_cast<const bf16x8v*>(Hm + (size_t)arow * HD + kk + ko);
        #pragma unroll
        for (int n = 0; n < 3; ++n) {
            bf16x8v b = *reinterpret_cast<const bf16x8v*>(Wt + (size_t)(n * 16 + l15) * HD + kk + ko);
            acc[n] = __builtin_amdgcn_mfma_f32_16x16x32_bf16(a, b, acc[n], 0, 0, 0);
        }
    }
    #pragma unroll
    for (int n = 0; n < 3; ++n) {
        int col = n * 16 + l15;
        if (col >= NCLS) continue;
        float bv = bias[col];
        #pragma unroll
        for (int i = 0; i < 4; ++i) {
            int row = r0 + (l >> 4) * 4 + i;
            if (row < M) out[(size_t)row * NCLS + col] = acc[n][i] + bv;
        }
    }
}

extern "C" void kernel_launch(void* const* d_in, const int* in_sizes, int n_in,
                              void* d_out, int out_size, void* d_ws, size_t ws_size,
                              hipStream_t stream)
{
    const float* x_in   = (const float*)d_in[0];
    const int*   vertex = (const int*)d_in[1];
    const int*   edges  = (const int*)d_in[2];
    const float* lin_w  = (const float*)d_in[3];
    const float* lin_b  = (const float*)d_in[4];
    const float* w1     = (const float*)d_in[5];
    const float* b1     = (const float*)d_in[6];
    const float* w2     = (const float*)d_in[7];
    const float* b2     = (const float*)d_in[8];
    const float* w3     = (const float*)d_in[9];
    const float* b3     = (const float*)d_in[10];
    const float* cw1    = (const float*)d_in[11];
    const float* cb1    = (const float*)d_in[12];
    const float* cw2    = (const float*)d_in[13];
    const float* cb2    = (const float*)d_in[14];
    float* out = (float*)d_out;
    (void)in_sizes; (void)n_in; (void)out_size; (void)ws_size;

    char* ws = (char*)d_ws;
    const size_t nvhd = (size_t)NV * HD, nehd = (size_t)NE * HD;
    size_t off = 0;
    auto alloc = [&](size_t bytes) { char* p = ws + off; off += (bytes + 255) & ~(size_t)255; return p; };
    bf16* x0 = (bf16*)alloc(nvhd * 2);          // restart anchor
    bf16* xA = (bf16*)alloc(nvhd * 2);          // layer output
    bf16* E1 = (bf16*)alloc(nehd * 2);          // T1 -> ge -> cls hidden
    bf16* E2 = (bf16*)alloc(nehd * 2);          // xe
    bf16* xf = (bf16*)alloc((size_t)NV * FINC * 2);   // x_in bf16; later S | z0
    bf16* S  = xf;                               // cur @ W23a   (xf dead after lin)
    bf16* z0 = xf + nvhd;                        // x0 @ w3
    unsigned short* lin_wt = (unsigned short*)alloc(256 * 512 * 2);
    unsigned short* w1t    = (unsigned short*)alloc(256 * 256 * 2);
    unsigned short* W23at  = (unsigned short*)alloc(256 * 256 * 2);  // MUST follow w1t
    unsigned short* W23bt  = (unsigned short*)alloc(256 * 256 * 2);
    unsigned short* w2a_nb = (unsigned short*)alloc(256 * 256 * 2);
    unsigned short* w2b_nb = (unsigned short*)alloc(256 * 256 * 2);
    unsigned short* w3t    = (unsigned short*)alloc(256 * 256 * 2);
    unsigned short* cw1t   = (unsigned short*)alloc(256 * 256 * 2);
    unsigned short* cw2t   = (unsigned short*)alloc(48 * 256 * 2);
    float* b2w3 = (float*)alloc(256 * 4);
    int* cnt_e = (int*)alloc(NE * 4);            // edge degree; cnt_v MUST follow
    int* cnt_v = (int*)alloc(NV * 4);            // vertex degree
    int* off_e = (int*)alloc((NE + 1) * 4);
    int* off_v = (int*)alloc((NV + 1) * 4);
    int* cur_e = (int*)alloc(NE * 4);
    int* cur_v = (int*)alloc(NV * 4);
    int* part_e = (int*)alloc(256 * 4);
    int* part_v = (int*)alloc(256 * 4);
    int* adj_e = (int*)alloc((size_t)NNZC * 4);
    int* adj_v = (int*)alloc((size_t)NNZC * 4);

    dim3 blk(256);
    dim3 gv((NV + 127) / 128, 2);    // 391 x 2  (Nc=256)
    dim3 gv4((NV + 127) / 128, 4);   // 391 x 4  (Nc=512 fused)
    dim3 gw(2, 2);                   // 256x256 weight compose

    // ---- CSR build ----
    fill0_k<<<128, blk, 0, stream>>>((unsigned int*)cnt_e, NE + NV);   // cnt_e ++ cnt_v contiguous
    hist_k<<<(NNZC + 255) / 256, blk, 0, stream>>>(vertex, edges, cnt_v, cnt_e, NNZC);
    scan_part_k<<<(NE + 1023) / 1024, blk, 0, stream>>>(cnt_e, off_e, part_e, NE);
    scan_part_k<<<(NV + 1023) / 1024, blk, 0, stream>>>(cnt_v, off_v, part_v, NV);
    scan_top_k<<<1, blk, 0, stream>>>(part_e, off_e + NE, (NE + 1023) / 1024);
    scan_top_k<<<1, blk, 0, stream>>>(part_v, off_v + NV, (NV + 1023) / 1024);
    scan_add_k<<<(NE + 255) / 256, blk, 0, stream>>>(off_e, part_e, NE);
    scan_add_k<<<(NV + 255) / 256, blk, 0, stream>>>(off_v, part_v, NV);
    copy2_k<<<128, blk, 0, stream>>>(off_e, cur_e, NE, off_v, cur_v, NV);
    csr_fill_k<<<(NNZC + 255) / 256, blk, 0, stream>>>(vertex, edges, cur_e, cur_v, adj_e, adj_v, NNZC);

    // ---- weight prep + composition ----
    prep_w_k<<<1840, blk, 0, stream>>>(lin_w, w1, w2, w3, cw1, cw2,
                                       lin_wt, w1t, w2a_nb, w2b_nb, w3t, cw1t, cw2t);
    b2w3_k<<<1, blk, 0, stream>>>(b2, w3, b2w3);
    // W23at[n][k] = sum_j w3t[n][j] * w2a[k][j]  ( = (w2a@w3)^T )
    mgemm_k<0><<<gw, blk, 0, stream>>>((const bf16*)w3t, (const bf16*)w2a_nb,
        nullptr, nullptr, nullptr, nullptr, nullptr, nullptr,
        (bf16*)W23at, nullptr, 256, 256, 256);
    mgemm_k<0><<<gw, blk, 0, stream>>>((const bf16*)w3t, (const bf16*)w2b_nb,
        nullptr, nullptr, nullptr, nullptr, nullptr, nullptr,
        (bf16*)W23bt, nullptr, 256, 256, 256);

    // ---- input projection ----
    xcvt_k<<<2048, blk, 0, stream>>>(x_in, (unsigned short*)xf, (long long)NV * FINC / 4);
    mgemm_k<1><<<gv, blk, 0, stream>>>(xf, (const bf16*)lin_wt,
        lin_b, nullptr, nullptr, nullptr, nullptr, nullptr,
        x0, nullptr, NV, FINC, HD);
    // z0 = x0 @ w3   (xf now dead; S/z0 occupy its region)
    mgemm_k<0><<<gv, blk, 0, stream>>>(x0, (const bf16*)w3t,
        nullptr, nullptr, nullptr, nullptr, nullptr, nullptr,
        z0, nullptr, NV, HD, HD);

    const bf16* cur = x0;
    for (int layer = 0; layer < 2; ++layer) {
        // E1(T1) = cur@w1 + b1 ; S = cur@W23a   (fused dual GEMM, Bt = [w1t ; W23at])
        mgemm_k<3><<<gv4, blk, 0, stream>>>(cur, (const bf16*)w1t,
            b1, nullptr, nullptr, nullptr, nullptr, nullptr,
            E1, S, NV, HD, 512);
        // E2(xe) = segment_sum(T1[vertex], edges)
        gather_sum_k<<<(NE + 3) / 4, blk, 0, stream>>>(E1, adj_e, off_e, E2, NE);
        // E1(ge) = segment_sum(xe[edges], vertex)
        gather_sum_k<<<(NV + 3) / 4, blk, 0, stream>>>(E2, adj_v, off_v, E1, NV);
        // xA = relu(0.5*(deg*(S + b2w3) + ge@W23b) + 0.5*z0 + b3)
        mgemm_k<4><<<gv, blk, 0, stream>>>(E1, (const bf16*)W23bt,
            b3, nullptr, cnt_v, S, z0, b2w3,
            xA, nullptr, NV, HD, HD);
        cur = xA;
    }

    // ---- classifier ----
    mgemm_k<1><<<gv, blk, 0, stream>>>(xA, (const bf16*)cw1t,
        cb1, nullptr, nullptr, nullptr, nullptr, nullptr,
        E1, nullptr, NV, HD, HD);
    cls_mfma_k<<<(NV + 63) / 64, blk, 0, stream>>>(E1, (const bf16*)cw2t, cb2, out, NV);
}

// Round 7
// 542.368 us; speedup vs baseline: 12.3149x; 1.1065x over previous
//
#include <hip/hip_runtime.h>
#include <hip/hip_bf16.h>
#include <cstdint>
#include <cstddef>

#define HD   256
#define NV   50000
#define NE   80000
#define NNZC 400000
#define FINC 512
#define NCLS 40

using bf16 = __hip_bfloat16;

typedef short bf16x8v __attribute__((ext_vector_type(8)));
typedef float f32x4   __attribute__((ext_vector_type(4)));

#define NCH_E ((NE + 1023) / 1024)   // 79
#define NCH_V ((NV + 1023) / 1024)   // 49

// ---------- dtype helpers ----------
__device__ __forceinline__ float b2f(unsigned short u) {
    union { unsigned int i; float f; } c; c.i = ((unsigned int)u) << 16; return c.f;
}
__device__ __forceinline__ unsigned short f2b(float f) {
    union { float f; unsigned int i; } c; c.f = f;
    return (unsigned short)((c.i + 0x7FFFu + ((c.i >> 16) & 1u)) >> 16);
}
__device__ __forceinline__ float4 load4f(const bf16* p) {
    ushort4 u = *reinterpret_cast<const ushort4*>(p);
    return make_float4(b2f(u.x), b2f(u.y), b2f(u.z), b2f(u.w));
}
__device__ __forceinline__ void store4(bf16* p, float4 v) {
    ushort4 u; u.x = f2b(v.x); u.y = f2b(v.y); u.z = f2b(v.z); u.w = f2b(v.w);
    *reinterpret_cast<ushort4*>(p) = u;
}

// ---------- async global->LDS, 16B per lane (LDS base wave-uniform) ----------
__device__ __forceinline__ void gl_lds16(const bf16* g, short* l) {
    __builtin_amdgcn_global_load_lds(
        (const __attribute__((address_space(1))) unsigned int*)g,
        (__attribute__((address_space(3))) unsigned int*)l,
        16, 0, 0);
}

// ---------- capture-safe zero fill ----------
__global__ __launch_bounds__(256)
void fill0_k(unsigned int* __restrict__ p, long long n)
{
    long long i = (long long)blockIdx.x * 256 + threadIdx.x;
    long long stride = (long long)gridDim.x * 256;
    for (; i < n; i += stride) p[i] = 0u;
}

// ---------- combined histogram ----------
__global__ __launch_bounds__(256)
void hist_k(const int* __restrict__ vertex, const int* __restrict__ edges,
            int* __restrict__ cnt_v, int* __restrict__ cnt_e, int nnz)
{
    int i = blockIdx.x * 256 + threadIdx.x;
    if (i < nnz) {
        atomicAdd(&cnt_v[vertex[i]], 1);
        atomicAdd(&cnt_e[edges[i]], 1);
    }
}

// ---------- merged 3-phase scan (y=0: edges, y=1: vertices) ----------
__global__ __launch_bounds__(256)
void scan_part2_k(const int* __restrict__ cnt_e, int* __restrict__ off_e, int* __restrict__ part_e,
                  const int* __restrict__ cnt_v, int* __restrict__ off_v, int* __restrict__ part_v)
{
    const int* cnt; int* off; int* part; int n;
    if (blockIdx.y == 0) { cnt = cnt_e; off = off_e; part = part_e; n = NE; }
    else                 { cnt = cnt_v; off = off_v; part = part_v; n = NV; }
    int base = blockIdx.x * 1024;
    if (base >= n) return;
    __shared__ int s[256];
    int idx = base + threadIdx.x * 4;
    int v[4], sum = 0;
    #pragma unroll
    for (int j = 0; j < 4; ++j) { v[j] = (idx + j < n) ? cnt[idx + j] : 0; sum += v[j]; }
    s[threadIdx.x] = sum;
    __syncthreads();
    #pragma unroll
    for (int d = 1; d < 256; d <<= 1) {
        int t = (threadIdx.x >= d) ? s[threadIdx.x - d] : 0;
        __syncthreads();
        s[threadIdx.x] += t;
        __syncthreads();
    }
    int excl = s[threadIdx.x] - sum;
    #pragma unroll
    for (int j = 0; j < 4; ++j) {
        if (idx + j < n) off[idx + j] = excl;
        excl += v[j];
    }
    if (threadIdx.x == 255) part[blockIdx.x] = s[255];
}

__global__ __launch_bounds__(256)
void scan_top2_k(int* __restrict__ part_e, int* __restrict__ end_e,
                 int* __restrict__ part_v, int* __restrict__ end_v)
{
    int* part; int* endp; int nch;
    if (blockIdx.x == 0) { part = part_e; endp = end_e; nch = NCH_E; }
    else                 { part = part_v; endp = end_v; nch = NCH_V; }
    __shared__ int s[256];
    int v = (threadIdx.x < nch) ? part[threadIdx.x] : 0;
    s[threadIdx.x] = v;
    __syncthreads();
    #pragma unroll
    for (int d = 1; d < 256; d <<= 1) {
        int t = (threadIdx.x >= d) ? s[threadIdx.x - d] : 0;
        __syncthreads();
        s[threadIdx.x] += t;
        __syncthreads();
    }
    if (threadIdx.x < nch) part[threadIdx.x] = s[threadIdx.x] - v;
    if (threadIdx.x == 255) *endp = s[255];
}

// off[i] += part[chunk]; cur[i] = off[i]
__global__ __launch_bounds__(256)
void scan_addcur2_k(int* __restrict__ off_e, const int* __restrict__ part_e, int* __restrict__ cur_e,
                    int* __restrict__ off_v, const int* __restrict__ part_v, int* __restrict__ cur_v)
{
    int n; int* off; const int* part; int* cur;
    if (blockIdx.y == 0) { n = NE; off = off_e; part = part_e; cur = cur_e; }
    else                 { n = NV; off = off_v; part = part_v; cur = cur_v; }
    int i = blockIdx.x * 256 + threadIdx.x;
    if (i < n) { int o = off[i] + part[i >> 10]; off[i] = o; cur[i] = o; }
}

// ---------- CSR adjacency fill ----------
__global__ __launch_bounds__(256)
void csr_fill_k(const int* __restrict__ vertex, const int* __restrict__ edges,
                int* __restrict__ cur_e, int* __restrict__ cur_v,
                int* __restrict__ adj_e, int* __restrict__ adj_v, int nnz)
{
    int i = blockIdx.x * 256 + threadIdx.x;
    if (i >= nnz) return;
    int v = vertex[i], e = edges[i];
    adj_e[atomicAdd(&cur_e[e], 1)] = v;
    adj_v[atomicAdd(&cur_v[v], 1)] = e;
}

// ---------- weight prep (+ b2w3 tail) ----------
__global__ __launch_bounds__(256)
void prep_w_k(const float* __restrict__ lin_w, const float* __restrict__ w1,
              const float* __restrict__ w2, const float* __restrict__ w3,
              const float* __restrict__ cw1, const float* __restrict__ cw2,
              const float* __restrict__ b2,
              unsigned short* __restrict__ lin_wt, unsigned short* __restrict__ w1t,
              unsigned short* __restrict__ w2a_nb, unsigned short* __restrict__ w2b_nb,
              unsigned short* __restrict__ w3t, unsigned short* __restrict__ cw1t,
              unsigned short* __restrict__ cw2t, float* __restrict__ b2w3)
{
    int idx = blockIdx.x * 256 + threadIdx.x;          // < 471296
    if (idx < 131072) { int n = idx >> 9, k = idx & 511; lin_wt[idx] = f2b(lin_w[k * 256 + n]); return; }
    idx -= 131072;
    if (idx < 65536) { int n = idx >> 8, k = idx & 255; w1t[idx] = f2b(w1[k * 256 + n]); return; }
    idx -= 65536;
    if (idx < 65536) { w2a_nb[idx] = f2b(w2[idx]); return; }
    idx -= 65536;
    if (idx < 65536) { w2b_nb[idx] = f2b(w2[65536 + idx]); return; }
    idx -= 65536;
    if (idx < 65536) { int n = idx >> 8, k = idx & 255; w3t[idx] = f2b(w3[k * 256 + n]); return; }
    idx -= 65536;
    if (idx < 65536) { int n = idx >> 8, k = idx & 255; cw1t[idx] = f2b(cw1[k * 256 + n]); return; }
    idx -= 65536;
    if (idx < 12288) { int n = idx >> 8, k = idx & 255; cw2t[idx] = f2b((n < NCLS) ? cw2[k * NCLS + n] : 0.f); return; }
    idx -= 12288;
    if (idx < 256) {
        float s = 0.f;
        for (int k = 0; k < 256; ++k) s += b2[k] * w3[k * 256 + idx];
        b2w3[idx] = s;
    }
}

// ---------- x_in f32 -> bf16 ----------
__global__ __launch_bounds__(256)
void xcvt_k(const float* __restrict__ x, unsigned short* __restrict__ o, long long n4)
{
    long long i = (long long)blockIdx.x * 256 + threadIdx.x;
    long long stride = (long long)gridDim.x * 256;
    for (; i < n4; i += stride) {
        float4 v = reinterpret_cast<const float4*>(x)[i];
        ushort4 u; u.x = f2b(v.x); u.y = f2b(v.y); u.z = f2b(v.z); u.w = f2b(v.w);
        reinterpret_cast<ushort4*>(o)[i] = u;
    }
}

// ---------- MFMA bf16 GEMM: 128x128 tile, BK=64, 4 waves ----------
// EPI 0: C = A@Bt^T (+bias)
// EPI 1: C = relu(A@Bt^T + bias)
// EPI 3: dual split (Nc=512): cols<256 -> Cg (+bias), cols>=256 -> Cg2 (+bias2), row stride 256
// EPI 4: C = relu(0.5*(deg[row]*(S+b2w3) + acc) + 0.5*z0 + bias)
// Grid: (Nc/128, ceil(M/128)) -- bn from x (fastest) so col-blocks of same rows are adjacent.
template<int EPI>
__global__ __launch_bounds__(256)
void mgemm_k(const bf16* __restrict__ Ag, const bf16* __restrict__ Bt,
             const float* __restrict__ bias, const float* __restrict__ bias2,
             const int* __restrict__ deg,
             const bf16* __restrict__ Sb, const bf16* __restrict__ z0b,
             const float* __restrict__ b2w3v,
             bf16* __restrict__ Cg, bf16* __restrict__ Cg2,
             int M, int K, int Nc)
{
    __shared__ __align__(16) short As[128 * 64];
    __shared__ __align__(16) short Bs[128 * 64];

    const int t  = threadIdx.x;
    const int wv = t >> 6, l = t & 63;
    const int wr = wv >> 1, wc = wv & 1;
    const int bn = blockIdx.x * 128;
    const int bm = blockIdx.y * 128;
    const int l15 = l & 15;

    f32x4 acc[4][4];
    #pragma unroll
    for (int m = 0; m < 4; ++m)
        #pragma unroll
        for (int n = 0; n < 4; ++n)
            acc[m][n] = (f32x4){0.f, 0.f, 0.f, 0.f};

    const int brow8 = l >> 3;          // staging: row within 8-row chunk
    const int bcol  = (l & 7) * 8;     // bf16 col within BK=64

    for (int k0 = 0; k0 < K; k0 += 64) {
        #pragma unroll
        for (int i = 0; i < 4; ++i) {
            int c = wv * 4 + i;
            int row = c * 8 + brow8;
            int ga = bm + row; if (ga >= M) ga = M - 1;
            gl_lds16(Ag + (size_t)ga * K + k0 + bcol, As + c * 512);
        }
        #pragma unroll
        for (int i = 0; i < 4; ++i) {
            int c = wv * 4 + i;
            int row = c * 8 + brow8;
            gl_lds16(Bt + (size_t)(bn + row) * K + k0 + bcol, Bs + c * 512);
        }
        __syncthreads();

        #pragma unroll
        for (int ks = 0; ks < 2; ++ks) {
            bf16x8v a[4], b[4];
            const int kb = ks * 64 + (l >> 4) * 16;
            #pragma unroll
            for (int m = 0; m < 4; ++m) {
                int r = wr * 64 + m * 16 + l15;
                a[m] = *reinterpret_cast<const bf16x8v*>((const char*)As + r * 128 + kb);
            }
            #pragma unroll
            for (int n = 0; n < 4; ++n) {
                int r = wc * 64 + n * 16 + l15;
                b[n] = *reinterpret_cast<const bf16x8v*>((const char*)Bs + r * 128 + kb);
            }
            #pragma unroll
            for (int m = 0; m < 4; ++m)
                #pragma unroll
                for (int n = 0; n < 4; ++n)
                    acc[m][n] = __builtin_amdgcn_mfma_f32_16x16x32_bf16(a[m], b[n], acc[m][n], 0, 0, 0);
        }
        __syncthreads();
    }

    if (EPI == 3) {
        bool second = (bn >= 256);
        bf16* CC = second ? Cg2 : Cg;
        const float* bb = second ? bias2 : bias;
        int cb = bn - (second ? 256 : 0);
        float bv[4];
        #pragma unroll
        for (int n = 0; n < 4; ++n)
            bv[n] = bb ? bb[cb + wc * 64 + n * 16 + l15] : 0.f;
        #pragma unroll
        for (int m = 0; m < 4; ++m) {
            #pragma unroll
            for (int i = 0; i < 4; ++i) {
                int row = bm + wr * 64 + m * 16 + (l >> 4) * 4 + i;
                if (row >= M) continue;
                size_t base = (size_t)row * 256 + cb + wc * 64 + l15;
                #pragma unroll
                for (int n = 0; n < 4; ++n)
                    reinterpret_cast<unsigned short*>(CC)[base + n * 16] = f2b(acc[m][n][i] + bv[n]);
            }
        }
    } else if (EPI == 4) {
        float bv[4], bw[4];
        #pragma unroll
        for (int n = 0; n < 4; ++n) {
            int col = bn + wc * 64 + n * 16 + l15;
            bv[n] = bias[col];
            bw[n] = b2w3v[col];
        }
        #pragma unroll
        for (int m = 0; m < 4; ++m) {
            #pragma unroll
            for (int i = 0; i < 4; ++i) {
                int row = bm + wr * 64 + m * 16 + (l >> 4) * 4 + i;
                if (row >= M) continue;
                float d = (float)deg[row];
                size_t base = (size_t)row * Nc + bn + wc * 64 + l15;
                #pragma unroll
                for (int n = 0; n < 4; ++n) {
                    size_t idx = base + (size_t)n * 16;
                    float sv = b2f(reinterpret_cast<const unsigned short*>(Sb)[idx]);
                    float zv = b2f(reinterpret_cast<const unsigned short*>(z0b)[idx]);
                    float v = 0.5f * (d * (sv + bw[n]) + acc[m][n][i]) + 0.5f * zv + bv[n];
                    v = fmaxf(v, 0.f);
                    reinterpret_cast<unsigned short*>(Cg)[idx] = f2b(v);
                }
            }
        }
    } else {
        float bv[4];
        #pragma unroll
        for (int n = 0; n < 4; ++n)
            bv[n] = bias ? bias[bn + wc * 64 + n * 16 + l15] : 0.f;
        #pragma unroll
        for (int m = 0; m < 4; ++m) {
            #pragma unroll
            for (int i = 0; i < 4; ++i) {
                int row = bm + wr * 64 + m * 16 + (l >> 4) * 4 + i;
                if (row >= M) continue;
                size_t base = (size_t)row * Nc + bn + wc * 64 + l15;
                #pragma unroll
                for (int n = 0; n < 4; ++n) {
                    float v = acc[m][n][i] + bv[n];
                    if (EPI == 1) v = fmaxf(v, 0.f);
                    reinterpret_cast<unsigned short*>(Cg)[base + n * 16] = f2b(v);
                }
            }
        }
    }
}

// ---------- gather segment-sum: dst[seg] = sum_{j in seg} src[adj[j]] ----------
__global__ __launch_bounds__(256)
void gather_sum_k(const bf16* __restrict__ src, const int* __restrict__ adj,
                  const int* __restrict__ off, bf16* __restrict__ dst, int nseg)
{
    int seg = blockIdx.x * 4 + (threadIdx.x >> 6);
    if (seg >= nseg) return;
    int lane = threadIdx.x & 63;
    int s0 = off[seg], s1 = off[seg + 1];
    float4 acc = make_float4(0.f, 0.f, 0.f, 0.f);
    int j = s0;
    for (; j + 2 <= s1; j += 2) {
        int r0 = adj[j], r1 = adj[j + 1];
        float4 v0 = load4f(src + (size_t)r0 * HD + lane * 4);
        float4 v1 = load4f(src + (size_t)r1 * HD + lane * 4);
        acc.x += v0.x + v1.x; acc.y += v0.y + v1.y;
        acc.z += v0.z + v1.z; acc.w += v0.w + v1.w;
    }
    if (j < s1) {
        float4 v = load4f(src + (size_t)adj[j] * HD + lane * 4);
        acc.x += v.x; acc.y += v.y; acc.z += v.z; acc.w += v.w;
    }
    store4(dst + (size_t)seg * HD + lane * 4, acc);
}

// ---------- MFMA classifier: out[M,40] = H[M,256] @ cw2t[48,256]^T + cb2 ----------
__global__ __launch_bounds__(256)
void cls_mfma_k(const bf16* __restrict__ Hm, const bf16* __restrict__ Wt,
                const float* __restrict__ bias, float* __restrict__ out, int M)
{
    const int wv = threadIdx.x >> 6, l = threadIdx.x & 63;
    const int l15 = l & 15;
    const int r0 = blockIdx.x * 64 + wv * 16;
    f32x4 acc[3];
    #pragma unroll
    for (int n = 0; n < 3; ++n) acc[n] = (f32x4){0.f, 0.f, 0.f, 0.f};

    int arow = r0 + l15; if (arow >= M) arow = M - 1;
    const int ko = (l >> 4) * 8;
    for (int kk = 0; kk < HD; kk += 32) {
        bf16x8v a = *reinterpret_cast<const bf16x8v*>(Hm + (size_t)arow * HD + kk + ko);
        #pragma unroll
        for (int n = 0; n < 3; ++n) {
            bf16x8v b = *reinterpret_cast<const bf16x8v*>(Wt + (size_t)(n * 16 + l15) * HD + kk + ko);
            acc[n] = __builtin_amdgcn_mfma_f32_16x16x32_bf16(a, b, acc[n], 0, 0, 0);
        }
    }
    #pragma unroll
    for (int n = 0; n < 3; ++n) {
        int col = n * 16 + l15;
        if (col >= NCLS) continue;
        float bv = bias[col];
        #pragma unroll
        for (int i = 0; i < 4; ++i) {
            int row = r0 + (l >> 4) * 4 + i;
            if (row < M) out[(size_t)row * NCLS + col] = acc[n][i] + bv;
        }
    }
}

extern "C" void kernel_launch(void* const* d_in, const int* in_sizes, int n_in,
                              void* d_out, int out_size, void* d_ws, size_t ws_size,
                              hipStream_t stream)
{
    const float* x_in   = (const float*)d_in[0];
    const int*   vertex = (const int*)d_in[1];
    const int*   edges  = (const int*)d_in[2];
    const float* lin_w  = (const float*)d_in[3];
    const float* lin_b  = (const float*)d_in[4];
    const float* w1     = (const float*)d_in[5];
    const float* b1     = (const float*)d_in[6];
    const float* w2     = (const float*)d_in[7];
    const float* b2     = (const float*)d_in[8];
    const float* w3     = (const float*)d_in[9];
    const float* b3     = (const float*)d_in[10];
    const float* cw1    = (const float*)d_in[11];
    const float* cb1    = (const float*)d_in[12];
    const float* cw2    = (const float*)d_in[13];
    const float* cb2    = (const float*)d_in[14];
    float* out = (float*)d_out;
    (void)in_sizes; (void)n_in; (void)out_size; (void)ws_size;

    char* ws = (char*)d_ws;
    const size_t nvhd = (size_t)NV * HD, nehd = (size_t)NE * HD;
    size_t off = 0;
    auto alloc = [&](size_t bytes) { char* p = ws + off; off += (bytes + 255) & ~(size_t)255; return p; };
    bf16* x0 = (bf16*)alloc(nvhd * 2);          // restart anchor
    bf16* xA = (bf16*)alloc(nvhd * 2);          // layer output
    bf16* E1 = (bf16*)alloc(nehd * 2);          // T1 -> ge -> cls hidden
    bf16* E2 = (bf16*)alloc(nehd * 2);          // xe
    bf16* xf = (bf16*)alloc((size_t)NV * FINC * 2);   // x_in bf16; dead after lin GEMM
    bf16* S  = xf;                               // cur @ W23a   (aliases dead xf)
    bf16* z0 = xf + nvhd;                        // x0 @ w3      (aliases dead xf)
    unsigned short* lin_wt = (unsigned short*)alloc(256 * 512 * 2);
    unsigned short* w1t    = (unsigned short*)alloc(256 * 256 * 2);  // [w1t ; W23at] must be adjacent
    unsigned short* W23at  = (unsigned short*)alloc(256 * 256 * 2);
    unsigned short* W23bt  = (unsigned short*)alloc(256 * 256 * 2);
    unsigned short* w2ab   = (unsigned short*)alloc(512 * 256 * 2);  // [w2a_nb ; w2b_nb]
    unsigned short* w2a_nb = w2ab;
    unsigned short* w2b_nb = w2ab + 256 * 256;
    unsigned short* w3t    = (unsigned short*)alloc(256 * 256 * 2);
    unsigned short* cw1t   = (unsigned short*)alloc(256 * 256 * 2);
    unsigned short* cw2t   = (unsigned short*)alloc(48 * 256 * 2);
    float* b2w3 = (float*)alloc(256 * 4);
    int* cnt_e = (int*)alloc(NE * 4);            // edge degree; cnt_v MUST follow (single fill)
    int* cnt_v = (int*)alloc(NV * 4);            // vertex degree (EPI4)
    int* off_e = (int*)alloc((NE + 1) * 4);
    int* off_v = (int*)alloc((NV + 1) * 4);
    int* cur_e = (int*)alloc(NE * 4);
    int* cur_v = (int*)alloc(NV * 4);
    int* part_e = (int*)alloc(256 * 4);
    int* part_v = (int*)alloc(256 * 4);
    int* adj_e = (int*)alloc((size_t)NNZC * 4);
    int* adj_v = (int*)alloc((size_t)NNZC * 4);

    dim3 blk(256);
    dim3 gv(2, (NV + 127) / 128);     // Nc=256 GEMMs over NV rows
    dim3 gv4(4, (NV + 127) / 128);    // Nc=512 dual GEMM
    dim3 gin(2, (NV + 127) / 128);    // lin GEMM (K=512)
    dim3 gw(4, 2);                    // 256x512 compose

    // ---- CSR build (6 launches) ----
    fill0_k<<<128, blk, 0, stream>>>((unsigned int*)cnt_e, NE + NV);
    hist_k<<<(NNZC + 255) / 256, blk, 0, stream>>>(vertex, edges, cnt_v, cnt_e, NNZC);
    scan_part2_k<<<dim3(NCH_E, 2), blk, 0, stream>>>(cnt_e, off_e, part_e, cnt_v, off_v, part_v);
    scan_top2_k<<<2, blk, 0, stream>>>(part_e, off_e + NE, part_v, off_v + NV);
    scan_addcur2_k<<<dim3((NE + 255) / 256, 2), blk, 0, stream>>>(off_e, part_e, cur_e,
                                                                  off_v, part_v, cur_v);
    csr_fill_k<<<(NNZC + 255) / 256, blk, 0, stream>>>(vertex, edges, cur_e, cur_v, adj_e, adj_v, NNZC);

    // ---- weight prep + composition (2 launches) ----
    prep_w_k<<<1841, blk, 0, stream>>>(lin_w, w1, w2, w3, cw1, cw2, b2,
                                       lin_wt, w1t, w2a_nb, w2b_nb, w3t, cw1t, cw2t, b2w3);
    // [W23at | W23bt] = w3t @ [w2a;w2b]^T  (EPI3 split-store, row stride 256 each)
    mgemm_k<3><<<gw, blk, 0, stream>>>((const bf16*)w3t, (const bf16*)w2ab,
        nullptr, nullptr, nullptr, nullptr, nullptr, nullptr,
        (bf16*)W23at, (bf16*)W23bt, 256, 256, 512);

    // ---- input projection (xcvt + bf16 GEMM; AF32 fused path removed: round-6 bisect) ----
    xcvt_k<<<2048, blk, 0, stream>>>(x_in, (unsigned short*)xf, (long long)NV * FINC / 4);
    mgemm_k<1><<<gin, blk, 0, stream>>>(xf, (const bf16*)lin_wt,
        lin_b, nullptr, nullptr, nullptr, nullptr, nullptr,
        x0, nullptr, NV, FINC, HD);
    // z0 = x0 @ w3   (xf dead from here; S/z0 occupy its region)
    mgemm_k<0><<<gv, blk, 0, stream>>>(x0, (const bf16*)w3t,
        nullptr, nullptr, nullptr, nullptr, nullptr, nullptr,
        z0, nullptr, NV, HD, HD);

    const bf16* cur = x0;
    for (int layer = 0; layer < 2; ++layer) {
        // E1(T1) = cur@w1 + b1 ; S = cur@W23a   (dual GEMM, Bt = [w1t ; W23at])
        mgemm_k<3><<<gv4, blk, 0, stream>>>(cur, (const bf16*)w1t,
            b1, nullptr, nullptr, nullptr, nullptr, nullptr,
            E1, S, NV, HD, 512);
        // E2(xe) = segment_sum(T1[vertex], edges)
        gather_sum_k<<<(NE + 3) / 4, blk, 0, stream>>>(E1, adj_e, off_e, E2, NE);
        // E1(ge) = segment_sum(xe[edges], vertex)
        gather_sum_k<<<(NV + 3) / 4, blk, 0, stream>>>(E2, adj_v, off_v, E1, NV);
        // xA = relu(0.5*(deg*(S + b2w3) + ge@W23b) + 0.5*z0 + b3)
        mgemm_k<4><<<gv, blk, 0, stream>>>(E1, (const bf16*)W23bt,
            b3, nullptr, cnt_v, S, z0, b2w3,
            xA, nullptr, NV, HD, HD);
        cur = xA;
    }

    // ---- classifier ----
    mgemm_k<1><<<gv, blk, 0, stream>>>(xA, (const bf16*)cw1t,
        cb1, nullptr, nullptr, nullptr, nullptr, nullptr,
        E1, nullptr, NV, HD, HD);
    cls_mfma_k<<<(NV + 63) / 64, blk, 0, stream>>>(E1, (const bf16*)cw2t, cb2, out, NV);
}

// Round 8
// 510.397 us; speedup vs baseline: 13.0863x; 1.0626x over previous
//
#include <hip/hip_runtime.h>
#include <hip/hip_bf16.h>
#include <cstdint>
#include <cstddef>

#define HD   256
#define NV   50000
#define NE   80000
#define NNZC 400000
#define FINC 512
#define NCLS 40

using bf16 = __hip_bfloat16;

typedef short bf16x8v __attribute__((ext_vector_type(8)));
typedef float f32x4   __attribute__((ext_vector_type(4)));

#define NCH_E ((NE + 1023) / 1024)   // 79
#define NCH_V ((NV + 1023) / 1024)   // 49

// ---------- dtype helpers ----------
__device__ __forceinline__ float b2f(unsigned short u) {
    union { unsigned int i; float f; } c; c.i = ((unsigned int)u) << 16; return c.f;
}
__device__ __forceinline__ unsigned short f2b(float f) {
    union { float f; unsigned int i; } c; c.f = f;
    return (unsigned short)((c.i + 0x7FFFu + ((c.i >> 16) & 1u)) >> 16);
}
__device__ __forceinline__ float4 load4f(const bf16* p) {
    ushort4 u = *reinterpret_cast<const ushort4*>(p);
    return make_float4(b2f(u.x), b2f(u.y), b2f(u.z), b2f(u.w));
}
__device__ __forceinline__ void store4(bf16* p, float4 v) {
    ushort4 u; u.x = f2b(v.x); u.y = f2b(v.y); u.z = f2b(v.z); u.w = f2b(v.w);
    *reinterpret_cast<ushort4*>(p) = u;
}

// ---------- async global->LDS, 16B per lane (LDS base wave-uniform) ----------
// NOTE (r6 lesson): only used for BF16 operand staging in the exact r4/r5-verified
// pattern. The f32 A-path uses reg-staging + ds_write instead (gl_lds f32 raced).
__device__ __forceinline__ void gl_lds16(const bf16* g, short* l) {
    __builtin_amdgcn_global_load_lds(
        (const __attribute__((address_space(1))) unsigned int*)g,
        (__attribute__((address_space(3))) unsigned int*)l,
        16, 0, 0);
}

// ---------- capture-safe zero fill ----------
__global__ __launch_bounds__(256)
void fill0_k(unsigned int* __restrict__ p, long long n)
{
    long long i = (long long)blockIdx.x * 256 + threadIdx.x;
    long long stride = (long long)gridDim.x * 256;
    for (; i < n; i += stride) p[i] = 0u;
}

// ---------- combined histogram ----------
__global__ __launch_bounds__(256)
void hist_k(const int* __restrict__ vertex, const int* __restrict__ edges,
            int* __restrict__ cnt_v, int* __restrict__ cnt_e, int nnz)
{
    int i = blockIdx.x * 256 + threadIdx.x;
    if (i < nnz) {
        atomicAdd(&cnt_v[vertex[i]], 1);
        atomicAdd(&cnt_e[edges[i]], 1);
    }
}

// ---------- merged 3-phase scan (y=0: edges, y=1: vertices) ----------
__global__ __launch_bounds__(256)
void scan_part2_k(const int* __restrict__ cnt_e, int* __restrict__ off_e, int* __restrict__ part_e,
                  const int* __restrict__ cnt_v, int* __restrict__ off_v, int* __restrict__ part_v)
{
    const int* cnt; int* off; int* part; int n;
    if (blockIdx.y == 0) { cnt = cnt_e; off = off_e; part = part_e; n = NE; }
    else                 { cnt = cnt_v; off = off_v; part = part_v; n = NV; }
    int base = blockIdx.x * 1024;
    if (base >= n) return;
    __shared__ int s[256];
    int idx = base + threadIdx.x * 4;
    int v[4], sum = 0;
    #pragma unroll
    for (int j = 0; j < 4; ++j) { v[j] = (idx + j < n) ? cnt[idx + j] : 0; sum += v[j]; }
    s[threadIdx.x] = sum;
    __syncthreads();
    #pragma unroll
    for (int d = 1; d < 256; d <<= 1) {
        int t = (threadIdx.x >= d) ? s[threadIdx.x - d] : 0;
        __syncthreads();
        s[threadIdx.x] += t;
        __syncthreads();
    }
    int excl = s[threadIdx.x] - sum;
    #pragma unroll
    for (int j = 0; j < 4; ++j) {
        if (idx + j < n) off[idx + j] = excl;
        excl += v[j];
    }
    if (threadIdx.x == 255) part[blockIdx.x] = s[255];
}

__global__ __launch_bounds__(256)
void scan_top2_k(int* __restrict__ part_e, int* __restrict__ end_e,
                 int* __restrict__ part_v, int* __restrict__ end_v)
{
    int* part; int* endp; int nch;
    if (blockIdx.x == 0) { part = part_e; endp = end_e; nch = NCH_E; }
    else                 { part = part_v; endp = end_v; nch = NCH_V; }
    __shared__ int s[256];
    int v = (threadIdx.x < nch) ? part[threadIdx.x] : 0;
    s[threadIdx.x] = v;
    __syncthreads();
    #pragma unroll
    for (int d = 1; d < 256; d <<= 1) {
        int t = (threadIdx.x >= d) ? s[threadIdx.x - d] : 0;
        __syncthreads();
        s[threadIdx.x] += t;
        __syncthreads();
    }
    if (threadIdx.x < nch) part[threadIdx.x] = s[threadIdx.x] - v;
    if (threadIdx.x == 255) *endp = s[255];
}

// off[i] += part[chunk]; cur[i] = off[i]
__global__ __launch_bounds__(256)
void scan_addcur2_k(int* __restrict__ off_e, const int* __restrict__ part_e, int* __restrict__ cur_e,
                    int* __restrict__ off_v, const int* __restrict__ part_v, int* __restrict__ cur_v)
{
    int n; int* off; const int* part; int* cur;
    if (blockIdx.y == 0) { n = NE; off = off_e; part = part_e; cur = cur_e; }
    else                 { n = NV; off = off_v; part = part_v; cur = cur_v; }
    int i = blockIdx.x * 256 + threadIdx.x;
    if (i < n) { int o = off[i] + part[i >> 10]; off[i] = o; cur[i] = o; }
}

// ---------- CSR adjacency fill ----------
__global__ __launch_bounds__(256)
void csr_fill_k(const int* __restrict__ vertex, const int* __restrict__ edges,
                int* __restrict__ cur_e, int* __restrict__ cur_v,
                int* __restrict__ adj_e, int* __restrict__ adj_v, int nnz)
{
    int i = blockIdx.x * 256 + threadIdx.x;
    if (i >= nnz) return;
    int v = vertex[i], e = edges[i];
    adj_e[atomicAdd(&cur_e[e], 1)] = v;
    adj_v[atomicAdd(&cur_v[v], 1)] = e;
}

// ---------- weight prep (+ b2w3 tail) ----------
__global__ __launch_bounds__(256)
void prep_w_k(const float* __restrict__ lin_w, const float* __restrict__ w1,
              const float* __restrict__ w2, const float* __restrict__ w3,
              const float* __restrict__ cw1, const float* __restrict__ cw2,
              const float* __restrict__ b2,
              unsigned short* __restrict__ lin_wt, unsigned short* __restrict__ w1t,
              unsigned short* __restrict__ w2a_nb, unsigned short* __restrict__ w2b_nb,
              unsigned short* __restrict__ w3t, unsigned short* __restrict__ cw1t,
              unsigned short* __restrict__ cw2t, float* __restrict__ b2w3)
{
    int idx = blockIdx.x * 256 + threadIdx.x;          // < 471296
    if (idx < 131072) { int n = idx >> 9, k = idx & 511; lin_wt[idx] = f2b(lin_w[k * 256 + n]); return; }
    idx -= 131072;
    if (idx < 65536) { int n = idx >> 8, k = idx & 255; w1t[idx] = f2b(w1[k * 256 + n]); return; }
    idx -= 65536;
    if (idx < 65536) { w2a_nb[idx] = f2b(w2[idx]); return; }
    idx -= 65536;
    if (idx < 65536) { w2b_nb[idx] = f2b(w2[65536 + idx]); return; }
    idx -= 65536;
    if (idx < 65536) { int n = idx >> 8, k = idx & 255; w3t[idx] = f2b(w3[k * 256 + n]); return; }
    idx -= 65536;
    if (idx < 65536) { int n = idx >> 8, k = idx & 255; cw1t[idx] = f2b(cw1[k * 256 + n]); return; }
    idx -= 65536;
    if (idx < 12288) { int n = idx >> 8, k = idx & 255; cw2t[idx] = f2b((n < NCLS) ? cw2[k * NCLS + n] : 0.f); return; }
    idx -= 12288;
    if (idx < 256) {
        float s = 0.f;
        for (int k = 0; k < 256; ++k) s += b2[k] * w3[k * 256 + idx];
        b2w3[idx] = s;
    }
}

// ---------- MFMA bf16 GEMM: 128x128 tile, BK=64, 4 waves ----------
// AF32: A is f32, staged via regular loads + in-register cvt + ds_write (safe path).
// EPI 0: C = A@Bt^T (+bias)
// EPI 1: C = relu(A@Bt^T + bias)
// EPI 3: multi split (Nc=256*k, k<=3): col-block oi=bn>>8 -> Cg/Cg2/Cg3 (+bias/bias2/none),
//        every output row-major [M][256]
// EPI 4: C = relu(0.5*(deg[row]*(S+b2w3) + acc) + 0.5*z0 + bias)
// Grid: (Nc/128, ceil(M/128)) -- bn from x (fastest) so col-blocks of same rows are adjacent.
template<int EPI, bool AF32>
__global__ __launch_bounds__(256)
void mgemm_k(const void* __restrict__ Agv, const bf16* __restrict__ Bt,
             const float* __restrict__ bias, const float* __restrict__ bias2,
             const int* __restrict__ deg,
             const bf16* __restrict__ Sb, const bf16* __restrict__ z0b,
             const float* __restrict__ b2w3v,
             bf16* __restrict__ Cg, bf16* __restrict__ Cg2, bf16* __restrict__ Cg3,
             int M, int K, int Nc)
{
    __shared__ __align__(16) short As[128 * 64];
    __shared__ __align__(16) short Bs[128 * 64];

    const int t  = threadIdx.x;
    const int wv = t >> 6, l = t & 63;
    const int wr = wv >> 1, wc = wv & 1;
    const int bn = blockIdx.x * 128;
    const int bm = blockIdx.y * 128;
    const int l15 = l & 15;

    f32x4 acc[4][4];
    #pragma unroll
    for (int m = 0; m < 4; ++m)
        #pragma unroll
        for (int n = 0; n < 4; ++n)
            acc[m][n] = (f32x4){0.f, 0.f, 0.f, 0.f};

    const int brow8 = l >> 3;          // staging: row within 8-row chunk
    const int bcol  = (l & 7) * 8;     // bf16 col within BK=64

    for (int k0 = 0; k0 < K; k0 += 64) {
        if constexpr (AF32) {
            // reg-staged f32 -> bf16: 4 passes x (256 thr x 8 floats) = 128x64 tile
            const float* Af = (const float*)Agv;
            #pragma unroll
            for (int p = 0; p < 4; ++p) {
                int idx8 = p * 256 + t;            // 0..1023
                int row  = idx8 >> 3;              // 0..127
                int cg   = (idx8 & 7) * 8;         // 0..56
                int ga = bm + row; if (ga >= M) ga = M - 1;
                const float* src = Af + (size_t)ga * K + k0 + cg;
                f32x4 u = *reinterpret_cast<const f32x4*>(src);
                f32x4 v = *reinterpret_cast<const f32x4*>(src + 4);
                bf16x8v o;
                o[0] = (short)f2b(u[0]); o[1] = (short)f2b(u[1]);
                o[2] = (short)f2b(u[2]); o[3] = (short)f2b(u[3]);
                o[4] = (short)f2b(v[0]); o[5] = (short)f2b(v[1]);
                o[6] = (short)f2b(v[2]); o[7] = (short)f2b(v[3]);
                *reinterpret_cast<bf16x8v*>(As + row * 64 + cg) = o;
            }
        } else {
            const bf16* Ab = (const bf16*)Agv;
            #pragma unroll
            for (int i = 0; i < 4; ++i) {
                int c = wv * 4 + i;
                int row = c * 8 + brow8;
                int ga = bm + row; if (ga >= M) ga = M - 1;
                gl_lds16(Ab + (size_t)ga * K + k0 + bcol, As + c * 512);
            }
        }
        #pragma unroll
        for (int i = 0; i < 4; ++i) {
            int c = wv * 4 + i;
            int row = c * 8 + brow8;
            gl_lds16(Bt + (size_t)(bn + row) * K + k0 + bcol, Bs + c * 512);
        }
        __syncthreads();

        #pragma unroll
        for (int ks = 0; ks < 2; ++ks) {
            bf16x8v a[4], b[4];
            const int kb = ks * 64 + (l >> 4) * 16;
            #pragma unroll
            for (int m = 0; m < 4; ++m) {
                int r = wr * 64 + m * 16 + l15;
                a[m] = *reinterpret_cast<const bf16x8v*>((const char*)As + r * 128 + kb);
            }
            #pragma unroll
            for (int n = 0; n < 4; ++n) {
                int r = wc * 64 + n * 16 + l15;
                b[n] = *reinterpret_cast<const bf16x8v*>((const char*)Bs + r * 128 + kb);
            }
            #pragma unroll
            for (int m = 0; m < 4; ++m)
                #pragma unroll
                for (int n = 0; n < 4; ++n)
                    acc[m][n] = __builtin_amdgcn_mfma_f32_16x16x32_bf16(a[m], b[n], acc[m][n], 0, 0, 0);
        }
        __syncthreads();
    }

    if (EPI == 3) {
        int oi = bn >> 8;
        bf16* CC = (oi == 0) ? Cg : (oi == 1) ? Cg2 : Cg3;
        const float* bb = (oi == 0) ? bias : (oi == 1) ? bias2 : nullptr;
        int cb = bn & 255;
        float bv[4];
        #pragma unroll
        for (int n = 0; n < 4; ++n)
            bv[n] = bb ? bb[cb + wc * 64 + n * 16 + l15] : 0.f;
        #pragma unroll
        for (int m = 0; m < 4; ++m) {
            #pragma unroll
            for (int i = 0; i < 4; ++i) {
                int row = bm + wr * 64 + m * 16 + (l >> 4) * 4 + i;
                if (row >= M) continue;
                size_t base = (size_t)row * 256 + cb + wc * 64 + l15;
                #pragma unroll
                for (int n = 0; n < 4; ++n)
                    reinterpret_cast<unsigned short*>(CC)[base + n * 16] = f2b(acc[m][n][i] + bv[n]);
            }
        }
    } else if (EPI == 4) {
        float bv[4], bw[4];
        #pragma unroll
        for (int n = 0; n < 4; ++n) {
            int col = bn + wc * 64 + n * 16 + l15;
            bv[n] = bias[col];
            bw[n] = b2w3v[col];
        }
        #pragma unroll
        for (int m = 0; m < 4; ++m) {
            #pragma unroll
            for (int i = 0; i < 4; ++i) {
                int row = bm + wr * 64 + m * 16 + (l >> 4) * 4 + i;
                if (row >= M) continue;
                float d = (float)deg[row];
                size_t base = (size_t)row * Nc + bn + wc * 64 + l15;
                #pragma unroll
                for (int n = 0; n < 4; ++n) {
                    size_t idx = base + (size_t)n * 16;
                    float sv = b2f(reinterpret_cast<const unsigned short*>(Sb)[idx]);
                    float zv = b2f(reinterpret_cast<const unsigned short*>(z0b)[idx]);
                    float v = 0.5f * (d * (sv + bw[n]) + acc[m][n][i]) + 0.5f * zv + bv[n];
                    v = fmaxf(v, 0.f);
                    reinterpret_cast<unsigned short*>(Cg)[idx] = f2b(v);
                }
            }
        }
    } else {
        float bv[4];
        #pragma unroll
        for (int n = 0; n < 4; ++n)
            bv[n] = bias ? bias[bn + wc * 64 + n * 16 + l15] : 0.f;
        #pragma unroll
        for (int m = 0; m < 4; ++m) {
            #pragma unroll
            for (int i = 0; i < 4; ++i) {
                int row = bm + wr * 64 + m * 16 + (l >> 4) * 4 + i;
                if (row >= M) continue;
                size_t base = (size_t)row * Nc + bn + wc * 64 + l15;
                #pragma unroll
                for (int n = 0; n < 4; ++n) {
                    float v = acc[m][n][i] + bv[n];
                    if (EPI == 1) v = fmaxf(v, 0.f);
                    reinterpret_cast<unsigned short*>(Cg)[base + n * 16] = f2b(v);
                }
            }
        }
    }
}

// ---------- gather segment-sum: dst[seg] = sum_{j in seg} src[adj[j]] ----------
__global__ __launch_bounds__(256)
void gather_sum_k(const bf16* __restrict__ src, const int* __restrict__ adj,
                  const int* __restrict__ off, bf16* __restrict__ dst, int nseg)
{
    int seg = blockIdx.x * 4 + (threadIdx.x >> 6);
    if (seg >= nseg) return;
    int lane = threadIdx.x & 63;
    int s0 = off[seg], s1 = off[seg + 1];
    float4 acc = make_float4(0.f, 0.f, 0.f, 0.f);
    int j = s0;
    for (; j + 4 <= s1; j += 4) {
        int r0 = adj[j], r1 = adj[j + 1], r2 = adj[j + 2], r3 = adj[j + 3];
        float4 v0 = load4f(src + (size_t)r0 * HD + lane * 4);
        float4 v1 = load4f(src + (size_t)r1 * HD + lane * 4);
        float4 v2 = load4f(src + (size_t)r2 * HD + lane * 4);
        float4 v3 = load4f(src + (size_t)r3 * HD + lane * 4);
        acc.x += (v0.x + v1.x) + (v2.x + v3.x);
        acc.y += (v0.y + v1.y) + (v2.y + v3.y);
        acc.z += (v0.z + v1.z) + (v2.z + v3.z);
        acc.w += (v0.w + v1.w) + (v2.w + v3.w);
    }
    for (; j < s1; ++j) {
        float4 v = load4f(src + (size_t)adj[j] * HD + lane * 4);
        acc.x += v.x; acc.y += v.y; acc.z += v.z; acc.w += v.w;
    }
    store4(dst + (size_t)seg * HD + lane * 4, acc);
}

// ---------- MFMA classifier: out[M,40] = H[M,256] @ cw2t[48,256]^T + cb2 ----------
__global__ __launch_bounds__(256)
void cls_mfma_k(const bf16* __restrict__ Hm, const bf16* __restrict__ Wt,
                const float* __restrict__ bias, float* __restrict__ out, int M)
{
    const int wv = threadIdx.x >> 6, l = threadIdx.x & 63;
    const int l15 = l & 15;
    const int r0 = blockIdx.x * 64 + wv * 16;
    f32x4 acc[3];
    #pragma unroll
    for (int n = 0; n < 3; ++n) acc[n] = (f32x4){0.f, 0.f, 0.f, 0.f};

    int arow = r0 + l15; if (arow >= M) arow = M - 1;
    const int ko = (l >> 4) * 8;
    for (int kk = 0; kk < HD; kk += 32) {
        bf16x8v a = *reinterpret_cast<const bf16x8v*>(Hm + (size_t)arow * HD + kk + ko);
        #pragma unroll
        for (int n = 0; n < 3; ++n) {
            bf16x8v b = *reinterpret_cast<const bf16x8v*>(Wt + (size_t)(n * 16 + l15) * HD + kk + ko);
            acc[n] = __builtin_amdgcn_mfma_f32_16x16x32_bf16(a, b, acc[n], 0, 0, 0);
        }
    }
    #pragma unroll
    for (int n = 0; n < 3; ++n) {
        int col = n * 16 + l15;
        if (col >= NCLS) continue;
        float bv = bias[col];
        #pragma unroll
        for (int i = 0; i < 4; ++i) {
            int row = r0 + (l >> 4) * 4 + i;
            if (row < M) out[(size_t)row * NCLS + col] = acc[n][i] + bv;
        }
    }
}

extern "C" void kernel_launch(void* const* d_in, const int* in_sizes, int n_in,
                              void* d_out, int out_size, void* d_ws, size_t ws_size,
                              hipStream_t stream)
{
    const float* x_in   = (const float*)d_in[0];
    const int*   vertex = (const int*)d_in[1];
    const int*   edges  = (const int*)d_in[2];
    const float* lin_w  = (const float*)d_in[3];
    const float* lin_b  = (const float*)d_in[4];
    const float* w1     = (const float*)d_in[5];
    const float* b1     = (const float*)d_in[6];
    const float* w2     = (const float*)d_in[7];
    const float* b2     = (const float*)d_in[8];
    const float* w3     = (const float*)d_in[9];
    const float* b3     = (const float*)d_in[10];
    const float* cw1    = (const float*)d_in[11];
    const float* cb1    = (const float*)d_in[12];
    const float* cw2    = (const float*)d_in[13];
    const float* cb2    = (const float*)d_in[14];
    float* out = (float*)d_out;
    (void)in_sizes; (void)n_in; (void)out_size; (void)ws_size;

    char* ws = (char*)d_ws;
    const size_t nvhd = (size_t)NV * HD, nehd = (size_t)NE * HD;
    size_t off = 0;
    auto alloc = [&](size_t bytes) { char* p = ws + off; off += (bytes + 255) & ~(size_t)255; return p; };
    bf16* x0 = (bf16*)alloc(nvhd * 2);          // restart anchor
    bf16* xA = (bf16*)alloc(nvhd * 2);          // layer output
    bf16* E1 = (bf16*)alloc(nehd * 2);          // T1 -> ge -> cls hidden
    bf16* E2 = (bf16*)alloc(nehd * 2);          // xe
    bf16* S  = (bf16*)alloc(nvhd * 2);          // cur @ W23a
    bf16* z0 = (bf16*)alloc(nvhd * 2);          // x0 @ w3
    // [w1t ; W23at ; w3t] MUST be contiguous (triple-GEMM B operand)
    unsigned short* w1t    = (unsigned short*)alloc(3 * 256 * 256 * 2);
    unsigned short* W23at  = w1t + 65536;
    unsigned short* w3t    = w1t + 131072;
    unsigned short* W23bt  = (unsigned short*)alloc(256 * 256 * 2);
    unsigned short* w2ab   = (unsigned short*)alloc(512 * 256 * 2);  // [w2a_nb ; w2b_nb]
    unsigned short* w2a_nb = w2ab;
    unsigned short* w2b_nb = w2ab + 256 * 256;
    unsigned short* lin_wt = (unsigned short*)alloc(256 * 512 * 2);
    unsigned short* cw1t   = (unsigned short*)alloc(256 * 256 * 2);
    unsigned short* cw2t   = (unsigned short*)alloc(48 * 256 * 2);
    float* b2w3 = (float*)alloc(256 * 4);
    int* cnt_e = (int*)alloc(NE * 4);            // edge degree; cnt_v MUST follow (single fill)
    int* cnt_v = (int*)alloc(NV * 4);            // vertex degree (EPI4)
    int* off_e = (int*)alloc((NE + 1) * 4);
    int* off_v = (int*)alloc((NV + 1) * 4);
    int* cur_e = (int*)alloc(NE * 4);
    int* cur_v = (int*)alloc(NV * 4);
    int* part_e = (int*)alloc(256 * 4);
    int* part_v = (int*)alloc(256 * 4);
    int* adj_e = (int*)alloc((size_t)NNZC * 4);
    int* adj_v = (int*)alloc((size_t)NNZC * 4);

    dim3 blk(256);
    dim3 gv(2, (NV + 127) / 128);     // Nc=256 GEMMs over NV rows
    dim3 gv4(4, (NV + 127) / 128);    // Nc=512 dual GEMM
    dim3 gv6(6, (NV + 127) / 128);    // Nc=768 triple GEMM
    dim3 gw(4, 2);                    // 256x512 compose

    // ---- CSR build (6 launches) ----
    fill0_k<<<128, blk, 0, stream>>>((unsigned int*)cnt_e, NE + NV);
    hist_k<<<(NNZC + 255) / 256, blk, 0, stream>>>(vertex, edges, cnt_v, cnt_e, NNZC);
    scan_part2_k<<<dim3(NCH_E, 2), blk, 0, stream>>>(cnt_e, off_e, part_e, cnt_v, off_v, part_v);
    scan_top2_k<<<2, blk, 0, stream>>>(part_e, off_e + NE, part_v, off_v + NV);
    scan_addcur2_k<<<dim3((NE + 255) / 256, 2), blk, 0, stream>>>(off_e, part_e, cur_e,
                                                                  off_v, part_v, cur_v);
    csr_fill_k<<<(NNZC + 255) / 256, blk, 0, stream>>>(vertex, edges, cur_e, cur_v, adj_e, adj_v, NNZC);

    // ---- weight prep + composition (2 launches) ----
    prep_w_k<<<1841, blk, 0, stream>>>(lin_w, w1, w2, w3, cw1, cw2, b2,
                                       lin_wt, w1t, w2a_nb, w2b_nb, w3t, cw1t, cw2t, b2w3);
    // [W23at | W23bt] = w3t @ [w2a;w2b]^T  (EPI3 split-store)
    mgemm_k<3, false><<<gw, blk, 0, stream>>>((const bf16*)w3t, (const bf16*)w2ab,
        nullptr, nullptr, nullptr, nullptr, nullptr, nullptr,
        (bf16*)W23at, (bf16*)W23bt, nullptr, 256, 256, 512);

    // ---- input projection: x0 = relu(x_in(f32) @ lin_w + lin_b), reg-staged A ----
    mgemm_k<1, true><<<gv, blk, 0, stream>>>(x_in, (const bf16*)lin_wt,
        lin_b, nullptr, nullptr, nullptr, nullptr, nullptr,
        x0, nullptr, nullptr, NV, FINC, HD);

    const bf16* cur = x0;
    for (int layer = 0; layer < 2; ++layer) {
        if (layer == 0) {
            // [E1(T1) | S | z0] = x0 @ [w1t ; W23at ; w3t]   (triple GEMM)
            mgemm_k<3, false><<<gv6, blk, 0, stream>>>(cur, (const bf16*)w1t,
                b1, nullptr, nullptr, nullptr, nullptr, nullptr,
                E1, S, z0, NV, HD, 768);
        } else {
            // [E1(T1) | S] = cur @ [w1t ; W23at]   (dual GEMM)
            mgemm_k<3, false><<<gv4, blk, 0, stream>>>(cur, (const bf16*)w1t,
                b1, nullptr, nullptr, nullptr, nullptr, nullptr,
                E1, S, nullptr, NV, HD, 512);
        }
        // E2(xe) = segment_sum(T1[vertex], edges)
        gather_sum_k<<<(NE + 3) / 4, blk, 0, stream>>>(E1, adj_e, off_e, E2, NE);
        // E1(ge) = segment_sum(xe[edges], vertex)
        gather_sum_k<<<(NV + 3) / 4, blk, 0, stream>>>(E2, adj_v, off_v, E1, NV);
        // xA = relu(0.5*(deg*(S + b2w3) + ge@W23b) + 0.5*z0 + b3)
        mgemm_k<4, false><<<gv, blk, 0, stream>>>(E1, (const bf16*)W23bt,
            b3, nullptr, cnt_v, S, z0, b2w3,
            xA, nullptr, nullptr, NV, HD, HD);
        cur = xA;
    }

    // ---- classifier ----
    mgemm_k<1, false><<<gv, blk, 0, stream>>>(xA, (const bf16*)cw1t,
        cb1, nullptr, nullptr, nullptr, nullptr, nullptr,
        E1, nullptr, nullptr, NV, HD, HD);
    cls_mfma_k<<<(NV + 63) / 64, blk, 0, stream>>>(E1, (const bf16*)cw2t, cb2, out, NV);
}

// Round 9
// 469.463 us; speedup vs baseline: 14.2274x; 1.0872x over previous
//
#include <hip/hip_runtime.h>
#include <hip/hip_bf16.h>
#include <cstdint>
#include <cstddef>

#define HD   256
#define NV   50000
#define NE   80000
#define NNZC 400000
#define FINC 512
#define NCLS 40

using bf16 = __hip_bfloat16;

typedef short bf16x8v __attribute__((ext_vector_type(8)));
typedef float f32x4   __attribute__((ext_vector_type(4)));

#define NCH_E ((NE + 1023) / 1024)   // 79
#define NCH_V ((NV + 1023) / 1024)   // 49

// ---------- dtype helpers ----------
__device__ __forceinline__ float b2f(unsigned short u) {
    union { unsigned int i; float f; } c; c.i = ((unsigned int)u) << 16; return c.f;
}
__device__ __forceinline__ unsigned short f2b(float f) {
    union { float f; unsigned int i; } c; c.f = f;
    return (unsigned short)((c.i + 0x7FFFu + ((c.i >> 16) & 1u)) >> 16);
}
__device__ __forceinline__ float4 load4f(const bf16* p) {
    ushort4 u = *reinterpret_cast<const ushort4*>(p);
    return make_float4(b2f(u.x), b2f(u.y), b2f(u.z), b2f(u.w));
}
__device__ __forceinline__ void store4(bf16* p, float4 v) {
    ushort4 u; u.x = f2b(v.x); u.y = f2b(v.y); u.z = f2b(v.z); u.w = f2b(v.w);
    *reinterpret_cast<ushort4*>(p) = u;
}

// ---------- async global->LDS, 16B per lane (LDS base wave-uniform, dest LINEAR) ----------
// r6 lesson: bf16 staging only, exact r4/r5 pattern. f32 A staged via regs+ds_write.
// r8: source global address is per-lane -> pre-swizzled source col gives swizzled LDS
// layout with linear dest (rule #21 correct form).
__device__ __forceinline__ void gl_lds16(const bf16* g, short* l) {
    __builtin_amdgcn_global_load_lds(
        (const __attribute__((address_space(1))) unsigned int*)g,
        (__attribute__((address_space(3))) unsigned int*)l,
        16, 0, 0);
}

// ---------- capture-safe zero fill ----------
__global__ __launch_bounds__(256)
void fill0_k(unsigned int* __restrict__ p, long long n)
{
    long long i = (long long)blockIdx.x * 256 + threadIdx.x;
    long long stride = (long long)gridDim.x * 256;
    for (; i < n; i += stride) p[i] = 0u;
}

// ---------- combined histogram ----------
__global__ __launch_bounds__(256)
void hist_k(const int* __restrict__ vertex, const int* __restrict__ edges,
            int* __restrict__ cnt_v, int* __restrict__ cnt_e, int nnz)
{
    int i = blockIdx.x * 256 + threadIdx.x;
    if (i < nnz) {
        atomicAdd(&cnt_v[vertex[i]], 1);
        atomicAdd(&cnt_e[edges[i]], 1);
    }
}

// ---------- merged 3-phase scan (y=0: edges, y=1: vertices) ----------
__global__ __launch_bounds__(256)
void scan_part2_k(const int* __restrict__ cnt_e, int* __restrict__ off_e, int* __restrict__ part_e,
                  const int* __restrict__ cnt_v, int* __restrict__ off_v, int* __restrict__ part_v)
{
    const int* cnt; int* off; int* part; int n;
    if (blockIdx.y == 0) { cnt = cnt_e; off = off_e; part = part_e; n = NE; }
    else                 { cnt = cnt_v; off = off_v; part = part_v; n = NV; }
    int base = blockIdx.x * 1024;
    if (base >= n) return;
    __shared__ int s[256];
    int idx = base + threadIdx.x * 4;
    int v[4], sum = 0;
    #pragma unroll
    for (int j = 0; j < 4; ++j) { v[j] = (idx + j < n) ? cnt[idx + j] : 0; sum += v[j]; }
    s[threadIdx.x] = sum;
    __syncthreads();
    #pragma unroll
    for (int d = 1; d < 256; d <<= 1) {
        int t = (threadIdx.x >= d) ? s[threadIdx.x - d] : 0;
        __syncthreads();
        s[threadIdx.x] += t;
        __syncthreads();
    }
    int excl = s[threadIdx.x] - sum;
    #pragma unroll
    for (int j = 0; j < 4; ++j) {
        if (idx + j < n) off[idx + j] = excl;
        excl += v[j];
    }
    if (threadIdx.x == 255) part[blockIdx.x] = s[255];
}

__global__ __launch_bounds__(256)
void scan_top2_k(int* __restrict__ part_e, int* __restrict__ end_e,
                 int* __restrict__ part_v, int* __restrict__ end_v)
{
    int* part; int* endp; int nch;
    if (blockIdx.x == 0) { part = part_e; endp = end_e; nch = NCH_E; }
    else                 { part = part_v; endp = end_v; nch = NCH_V; }
    __shared__ int s[256];
    int v = (threadIdx.x < nch) ? part[threadIdx.x] : 0;
    s[threadIdx.x] = v;
    __syncthreads();
    #pragma unroll
    for (int d = 1; d < 256; d <<= 1) {
        int t = (threadIdx.x >= d) ? s[threadIdx.x - d] : 0;
        __syncthreads();
        s[threadIdx.x] += t;
        __syncthreads();
    }
    if (threadIdx.x < nch) part[threadIdx.x] = s[threadIdx.x] - v;
    if (threadIdx.x == 255) *endp = s[255];
}

// off[i] += part[chunk]; cur[i] = off[i]
__global__ __launch_bounds__(256)
void scan_addcur2_k(int* __restrict__ off_e, const int* __restrict__ part_e, int* __restrict__ cur_e,
                    int* __restrict__ off_v, const int* __restrict__ part_v, int* __restrict__ cur_v)
{
    int n; int* off; const int* part; int* cur;
    if (blockIdx.y == 0) { n = NE; off = off_e; part = part_e; cur = cur_e; }
    else                 { n = NV; off = off_v; part = part_v; cur = cur_v; }
    int i = blockIdx.x * 256 + threadIdx.x;
    if (i < n) { int o = off[i] + part[i >> 10]; off[i] = o; cur[i] = o; }
}

// ---------- CSR adjacency fill ----------
__global__ __launch_bounds__(256)
void csr_fill_k(const int* __restrict__ vertex, const int* __restrict__ edges,
                int* __restrict__ cur_e, int* __restrict__ cur_v,
                int* __restrict__ adj_e, int* __restrict__ adj_v, int nnz)
{
    int i = blockIdx.x * 256 + threadIdx.x;
    if (i >= nnz) return;
    int v = vertex[i], e = edges[i];
    adj_e[atomicAdd(&cur_e[e], 1)] = v;
    adj_v[atomicAdd(&cur_v[v], 1)] = e;
}

// ---------- weight prep (+ b2w3 tail) ----------
__global__ __launch_bounds__(256)
void prep_w_k(const float* __restrict__ lin_w, const float* __restrict__ w1,
              const float* __restrict__ w2, const float* __restrict__ w3,
              const float* __restrict__ cw1, const float* __restrict__ cw2,
              const float* __restrict__ b2,
              unsigned short* __restrict__ lin_wt, unsigned short* __restrict__ w1t,
              unsigned short* __restrict__ w2a_nb, unsigned short* __restrict__ w2b_nb,
              unsigned short* __restrict__ w3t, unsigned short* __restrict__ cw1t,
              unsigned short* __restrict__ cw2t, float* __restrict__ b2w3)
{
    int idx = blockIdx.x * 256 + threadIdx.x;          // < 471296
    if (idx < 131072) { int n = idx >> 9, k = idx & 511; lin_wt[idx] = f2b(lin_w[k * 256 + n]); return; }
    idx -= 131072;
    if (idx < 65536) { int n = idx >> 8, k = idx & 255; w1t[idx] = f2b(w1[k * 256 + n]); return; }
    idx -= 65536;
    if (idx < 65536) { w2a_nb[idx] = f2b(w2[idx]); return; }
    idx -= 65536;
    if (idx < 65536) { w2b_nb[idx] = f2b(w2[65536 + idx]); return; }
    idx -= 65536;
    if (idx < 65536) { int n = idx >> 8, k = idx & 255; w3t[idx] = f2b(w3[k * 256 + n]); return; }
    idx -= 65536;
    if (idx < 65536) { int n = idx >> 8, k = idx & 255; cw1t[idx] = f2b(cw1[k * 256 + n]); return; }
    idx -= 65536;
    if (idx < 12288) { int n = idx >> 8, k = idx & 255; cw2t[idx] = f2b((n < NCLS) ? cw2[k * NCLS + n] : 0.f); return; }
    idx -= 12288;
    if (idx < 256) {
        float s = 0.f;
        for (int k = 0; k < 256; ++k) s += b2[k] * w3[k * 256 + idx];
        b2w3[idx] = s;
    }
}

// ---------- MFMA bf16 GEMM: 128x128 tile, BK=64, 4 waves ----------
// r8 additions:
//  * 1-D XCD-grouped grid: p -> {xcd=p&7, q=p>>3, cblk=q%nbn, rblk=q/nbn, r=rblk*8+xcd}
//    so the nbn col-blocks of one row panel are 8 apart in linear id -> same XCD L2.
//  * LDS st-swizzle: source col ((l&7)^(l>>3))*8 with linear LDS dest; reads XOR
//    byte offset with (row&7)<<4. Breaks the 16-way ds_read_b128 bank conflict.
// EPI 0: C = A@Bt^T (+bias); EPI 1: + relu
// EPI 3: multi split (Nc=256*k, k<=3): col-block oi -> Cg/Cg2/Cg3, each [M][256]
// EPI 4: C = relu(0.5*(deg[row]*(S+b2w3) + acc) + 0.5*z0 + bias)
template<int EPI, bool AF32>
__global__ __launch_bounds__(256)
void mgemm_k(const void* __restrict__ Agv, const bf16* __restrict__ Bt,
             const float* __restrict__ bias, const float* __restrict__ bias2,
             const int* __restrict__ deg,
             const bf16* __restrict__ Sb, const bf16* __restrict__ z0b,
             const float* __restrict__ b2w3v,
             bf16* __restrict__ Cg, bf16* __restrict__ Cg2, bf16* __restrict__ Cg3,
             int M, int K, int Nc)
{
    const int nbn = Nc >> 7;
    const int nbm = (M + 127) >> 7;
    const int p   = blockIdx.x;
    const int xcd = p & 7;
    const int q   = p >> 3;
    const int cblk = q % nbn;
    const int rblk = q / nbn;
    const int rb   = rblk * 8 + xcd;
    if (rb >= nbm) return;                 // block-uniform exit (before any barrier)
    const int bn = cblk * 128;
    const int bm = rb * 128;

    __shared__ __align__(16) short As[128 * 64];
    __shared__ __align__(16) short Bs[128 * 64];

    const int t  = threadIdx.x;
    const int wv = t >> 6, l = t & 63;
    const int wr = wv >> 1, wc = wv & 1;
    const int l15 = l & 15;

    f32x4 acc[4][4];
    #pragma unroll
    for (int m = 0; m < 4; ++m)
        #pragma unroll
        for (int n = 0; n < 4; ++n)
            acc[m][n] = (f32x4){0.f, 0.f, 0.f, 0.f};

    const int brow8   = l >> 3;                       // row within 8-row chunk
    const int bcol_sw = (((l & 7) ^ (l >> 3)) * 8);   // PRE-SWIZZLED source col (bf16)

    for (int k0 = 0; k0 < K; k0 += 64) {
        if constexpr (AF32) {
            // reg-staged f32 -> bf16, ds_write with swizzled address
            const float* Af = (const float*)Agv;
            #pragma unroll
            for (int pi = 0; pi < 4; ++pi) {
                int idx8 = pi * 256 + t;            // 0..1023
                int row  = idx8 >> 3;               // 0..127
                int cg   = (idx8 & 7) * 8;          // bf16 elems 0..56
                int ga = bm + row; if (ga >= M) ga = M - 1;
                const float* src = Af + (size_t)ga * K + k0 + cg;
                f32x4 u = *reinterpret_cast<const f32x4*>(src);
                f32x4 v = *reinterpret_cast<const f32x4*>(src + 4);
                bf16x8v o;
                o[0] = (short)f2b(u[0]); o[1] = (short)f2b(u[1]);
                o[2] = (short)f2b(u[2]); o[3] = (short)f2b(u[3]);
                o[4] = (short)f2b(v[0]); o[5] = (short)f2b(v[1]);
                o[6] = (short)f2b(v[2]); o[7] = (short)f2b(v[3]);
                *reinterpret_cast<bf16x8v*>(As + row * 64 + (cg ^ ((row & 7) * 8))) = o;
            }
        } else {
            const bf16* Ab = (const bf16*)Agv;
            #pragma unroll
            for (int i = 0; i < 4; ++i) {
                int c = wv * 4 + i;
                int row = c * 8 + brow8;
                int ga = bm + row; if (ga >= M) ga = M - 1;
                gl_lds16(Ab + (size_t)ga * K + k0 + bcol_sw, As + c * 512);
            }
        }
        #pragma unroll
        for (int i = 0; i < 4; ++i) {
            int c = wv * 4 + i;
            int row = c * 8 + brow8;
            gl_lds16(Bt + (size_t)(bn + row) * K + k0 + bcol_sw, Bs + c * 512);
        }
        __syncthreads();

        #pragma unroll
        for (int ks = 0; ks < 2; ++ks) {
            bf16x8v a[4], b[4];
            const int kb = ks * 64 + (l >> 4) * 16;   // byte offset pre-swizzle
            #pragma unroll
            for (int m = 0; m < 4; ++m) {
                int r = wr * 64 + m * 16 + l15;
                a[m] = *reinterpret_cast<const bf16x8v*>(
                           (const char*)As + r * 128 + (kb ^ ((r & 7) << 4)));
            }
            #pragma unroll
            for (int n = 0; n < 4; ++n) {
                int r = wc * 64 + n * 16 + l15;
                b[n] = *reinterpret_cast<const bf16x8v*>(
                           (const char*)Bs + r * 128 + (kb ^ ((r & 7) << 4)));
            }
            #pragma unroll
            for (int m = 0; m < 4; ++m)
                #pragma unroll
                for (int n = 0; n < 4; ++n)
                    acc[m][n] = __builtin_amdgcn_mfma_f32_16x16x32_bf16(a[m], b[n], acc[m][n], 0, 0, 0);
        }
        __syncthreads();
    }

    if (EPI == 3) {
        int oi = bn >> 8;
        bf16* CC = (oi == 0) ? Cg : (oi == 1) ? Cg2 : Cg3;
        const float* bb = (oi == 0) ? bias : (oi == 1) ? bias2 : nullptr;
        int cb = bn & 255;
        float bv[4];
        #pragma unroll
        for (int n = 0; n < 4; ++n)
            bv[n] = bb ? bb[cb + wc * 64 + n * 16 + l15] : 0.f;
        #pragma unroll
        for (int m = 0; m < 4; ++m) {
            #pragma unroll
            for (int i = 0; i < 4; ++i) {
                int row = bm + wr * 64 + m * 16 + (l >> 4) * 4 + i;
                if (row >= M) continue;
                size_t base = (size_t)row * 256 + cb + wc * 64 + l15;
                #pragma unroll
                for (int n = 0; n < 4; ++n)
                    reinterpret_cast<unsigned short*>(CC)[base + n * 16] = f2b(acc[m][n][i] + bv[n]);
            }
        }
    } else if (EPI == 4) {
        float bv[4], bw[4];
        #pragma unroll
        for (int n = 0; n < 4; ++n) {
            int col = bn + wc * 64 + n * 16 + l15;
            bv[n] = bias[col];
            bw[n] = b2w3v[col];
        }
        #pragma unroll
        for (int m = 0; m < 4; ++m) {
            #pragma unroll
            for (int i = 0; i < 4; ++i) {
                int row = bm + wr * 64 + m * 16 + (l >> 4) * 4 + i;
                if (row >= M) continue;
                float d = (float)deg[row];
                size_t base = (size_t)row * Nc + bn + wc * 64 + l15;
                #pragma unroll
                for (int n = 0; n < 4; ++n) {
                    size_t idx = base + (size_t)n * 16;
                    float sv = b2f(reinterpret_cast<const unsigned short*>(Sb)[idx]);
                    float zv = b2f(reinterpret_cast<const unsigned short*>(z0b)[idx]);
                    float v = 0.5f * (d * (sv + bw[n]) + acc[m][n][i]) + 0.5f * zv + bv[n];
                    v = fmaxf(v, 0.f);
                    reinterpret_cast<unsigned short*>(Cg)[idx] = f2b(v);
                }
            }
        }
    } else {
        float bv[4];
        #pragma unroll
        for (int n = 0; n < 4; ++n)
            bv[n] = bias ? bias[bn + wc * 64 + n * 16 + l15] : 0.f;
        #pragma unroll
        for (int m = 0; m < 4; ++m) {
            #pragma unroll
            for (int i = 0; i < 4; ++i) {
                int row = bm + wr * 64 + m * 16 + (l >> 4) * 4 + i;
                if (row >= M) continue;
                size_t base = (size_t)row * Nc + bn + wc * 64 + l15;
                #pragma unroll
                for (int n = 0; n < 4; ++n) {
                    float v = acc[m][n][i] + bv[n];
                    if (EPI == 1) v = fmaxf(v, 0.f);
                    reinterpret_cast<unsigned short*>(Cg)[base + n * 16] = f2b(v);
                }
            }
        }
    }
}

// ---------- gather segment-sum: dst[seg] = sum_{j in seg} src[adj[j]] ----------
__global__ __launch_bounds__(256)
void gather_sum_k(const bf16* __restrict__ src, const int* __restrict__ adj,
                  const int* __restrict__ off, bf16* __restrict__ dst, int nseg)
{
    int seg = blockIdx.x * 4 + (threadIdx.x >> 6);
    if (seg >= nseg) return;
    int lane = threadIdx.x & 63;
    int s0 = off[seg], s1 = off[seg + 1];
    float4 acc = make_float4(0.f, 0.f, 0.f, 0.f);
    int j = s0;
    for (; j + 4 <= s1; j += 4) {
        int r0 = adj[j], r1 = adj[j + 1], r2 = adj[j + 2], r3 = adj[j + 3];
        float4 v0 = load4f(src + (size_t)r0 * HD + lane * 4);
        float4 v1 = load4f(src + (size_t)r1 * HD + lane * 4);
        float4 v2 = load4f(src + (size_t)r2 * HD + lane * 4);
        float4 v3 = load4f(src + (size_t)r3 * HD + lane * 4);
        acc.x += (v0.x + v1.x) + (v2.x + v3.x);
        acc.y += (v0.y + v1.y) + (v2.y + v3.y);
        acc.z += (v0.z + v1.z) + (v2.z + v3.z);
        acc.w += (v0.w + v1.w) + (v2.w + v3.w);
    }
    for (; j < s1; ++j) {
        float4 v = load4f(src + (size_t)adj[j] * HD + lane * 4);
        acc.x += v.x; acc.y += v.y; acc.z += v.z; acc.w += v.w;
    }
    store4(dst + (size_t)seg * HD + lane * 4, acc);
}

// ---------- MFMA classifier: out[M,40] = H[M,256] @ cw2t[48,256]^T + cb2 ----------
__global__ __launch_bounds__(256)
void cls_mfma_k(const bf16* __restrict__ Hm, const bf16* __restrict__ Wt,
                const float* __restrict__ bias, float* __restrict__ out, int M)
{
    const int wv = threadIdx.x >> 6, l = threadIdx.x & 63;
    const int l15 = l & 15;
    const int r0 = blockIdx.x * 64 + wv * 16;
    f32x4 acc[3];
    #pragma unroll
    for (int n = 0; n < 3; ++n) acc[n] = (f32x4){0.f, 0.f, 0.f, 0.f};

    int arow = r0 + l15; if (arow >= M) arow = M - 1;
    const int ko = (l >> 4) * 8;
    for (int kk = 0; kk < HD; kk += 32) {
        bf16x8v a = *reinterpret_cast<const bf16x8v*>(Hm + (size_t)arow * HD + kk + ko);
        #pragma unroll
        for (int n = 0; n < 3; ++n) {
            bf16x8v b = *reinterpret_cast<const bf16x8v*>(Wt + (size_t)(n * 16 + l15) * HD + kk + ko);
            acc[n] = __builtin_amdgcn_mfma_f32_16x16x32_bf16(a, b, acc[n], 0, 0, 0);
        }
    }
    #pragma unroll
    for (int n = 0; n < 3; ++n) {
        int col = n * 16 + l15;
        if (col >= NCLS) continue;
        float bv = bias[col];
        #pragma unroll
        for (int i = 0; i < 4; ++i) {
            int row = r0 + (l >> 4) * 4 + i;
            if (row < M) out[(size_t)row * NCLS + col] = acc[n][i] + bv;
        }
    }
}

// XCD-grouped 1-D grid size for an (M, Nc) GEMM
static inline int xcd_grid(int M, int Nc)
{
    int nbm = (M + 127) >> 7;
    int nbn = Nc >> 7;
    return nbn * (((nbm + 7) / 8) * 8);
}

extern "C" void kernel_launch(void* const* d_in, const int* in_sizes, int n_in,
                              void* d_out, int out_size, void* d_ws, size_t ws_size,
                              hipStream_t stream)
{
    const float* x_in   = (const float*)d_in[0];
    const int*   vertex = (const int*)d_in[1];
    const int*   edges  = (const int*)d_in[2];
    const float* lin_w  = (const float*)d_in[3];
    const float* lin_b  = (const float*)d_in[4];
    const float* w1     = (const float*)d_in[5];
    const float* b1     = (const float*)d_in[6];
    const float* w2     = (const float*)d_in[7];
    const float* b2     = (const float*)d_in[8];
    const float* w3     = (const float*)d_in[9];
    const float* b3     = (const float*)d_in[10];
    const float* cw1    = (const float*)d_in[11];
    const float* cb1    = (const float*)d_in[12];
    const float* cw2    = (const float*)d_in[13];
    const float* cb2    = (const float*)d_in[14];
    float* out = (float*)d_out;
    (void)in_sizes; (void)n_in; (void)out_size; (void)ws_size;

    char* ws = (char*)d_ws;
    const size_t nvhd = (size_t)NV * HD, nehd = (size_t)NE * HD;
    size_t off = 0;
    auto alloc = [&](size_t bytes) { char* p = ws + off; off += (bytes + 255) & ~(size_t)255; return p; };
    bf16* x0 = (bf16*)alloc(nvhd * 2);          // restart anchor
    bf16* xA = (bf16*)alloc(nvhd * 2);          // layer output
    bf16* E1 = (bf16*)alloc(nehd * 2);          // T1 -> ge -> cls hidden
    bf16* E2 = (bf16*)alloc(nehd * 2);          // xe
    bf16* S  = (bf16*)alloc(nvhd * 2);          // cur @ W23a
    bf16* z0 = (bf16*)alloc(nvhd * 2);          // x0 @ w3
    // [w1t ; W23at ; w3t] MUST be contiguous (triple-GEMM B operand)
    unsigned short* w1t    = (unsigned short*)alloc(3 * 256 * 256 * 2);
    unsigned short* W23at  = w1t + 65536;
    unsigned short* w3t    = w1t + 131072;
    unsigned short* W23bt  = (unsigned short*)alloc(256 * 256 * 2);
    unsigned short* w2ab   = (unsigned short*)alloc(512 * 256 * 2);  // [w2a_nb ; w2b_nb]
    unsigned short* w2a_nb = w2ab;
    unsigned short* w2b_nb = w2ab + 256 * 256;
    unsigned short* lin_wt = (unsigned short*)alloc(256 * 512 * 2);
    unsigned short* cw1t   = (unsigned short*)alloc(256 * 256 * 2);
    unsigned short* cw2t   = (unsigned short*)alloc(48 * 256 * 2);
    float* b2w3 = (float*)alloc(256 * 4);
    int* cnt_e = (int*)alloc(NE * 4);            // edge degree; cnt_v MUST follow (single fill)
    int* cnt_v = (int*)alloc(NV * 4);            // vertex degree (EPI4)
    int* off_e = (int*)alloc((NE + 1) * 4);
    int* off_v = (int*)alloc((NV + 1) * 4);
    int* cur_e = (int*)alloc(NE * 4);
    int* cur_v = (int*)alloc(NV * 4);
    int* part_e = (int*)alloc(256 * 4);
    int* part_v = (int*)alloc(256 * 4);
    int* adj_e = (int*)alloc((size_t)NNZC * 4);
    int* adj_v = (int*)alloc((size_t)NNZC * 4);

    dim3 blk(256);

    // ---- CSR build (6 launches) ----
    fill0_k<<<128, blk, 0, stream>>>((unsigned int*)cnt_e, NE + NV);
    hist_k<<<(NNZC + 255) / 256, blk, 0, stream>>>(vertex, edges, cnt_v, cnt_e, NNZC);
    scan_part2_k<<<dim3(NCH_E, 2), blk, 0, stream>>>(cnt_e, off_e, part_e, cnt_v, off_v, part_v);
    scan_top2_k<<<2, blk, 0, stream>>>(part_e, off_e + NE, part_v, off_v + NV);
    scan_addcur2_k<<<dim3((NE + 255) / 256, 2), blk, 0, stream>>>(off_e, part_e, cur_e,
                                                                  off_v, part_v, cur_v);
    csr_fill_k<<<(NNZC + 255) / 256, blk, 0, stream>>>(vertex, edges, cur_e, cur_v, adj_e, adj_v, NNZC);

    // ---- weight prep + composition (2 launches) ----
    prep_w_k<<<1841, blk, 0, stream>>>(lin_w, w1, w2, w3, cw1, cw2, b2,
                                       lin_wt, w1t, w2a_nb, w2b_nb, w3t, cw1t, cw2t, b2w3);
    // [W23at | W23bt] = w3t @ [w2a;w2b]^T  (EPI3 split-store)
    mgemm_k<3, false><<<xcd_grid(256, 512), blk, 0, stream>>>((const bf16*)w3t, (const bf16*)w2ab,
        nullptr, nullptr, nullptr, nullptr, nullptr, nullptr,
        (bf16*)W23at, (bf16*)W23bt, nullptr, 256, 256, 512);

    // ---- input projection: x0 = relu(x_in(f32) @ lin_w + lin_b), reg-staged A ----
    mgemm_k<1, true><<<xcd_grid(NV, 256), blk, 0, stream>>>(x_in, (const bf16*)lin_wt,
        lin_b, nullptr, nullptr, nullptr, nullptr, nullptr,
        x0, nullptr, nullptr, NV, FINC, HD);

    const bf16* cur = x0;
    for (int layer = 0; layer < 2; ++layer) {
        if (layer == 0) {
            // [E1(T1) | S | z0] = x0 @ [w1t ; W23at ; w3t]   (triple GEMM)
            mgemm_k<3, false><<<xcd_grid(NV, 768), blk, 0, stream>>>(cur, (const bf16*)w1t,
                b1, nullptr, nullptr, nullptr, nullptr, nullptr,
                E1, S, z0, NV, HD, 768);
        } else {
            // [E1(T1) | S] = cur @ [w1t ; W23at]   (dual GEMM)
            mgemm_k<3, false><<<xcd_grid(NV, 512), blk, 0, stream>>>(cur, (const bf16*)w1t,
                b1, nullptr, nullptr, nullptr, nullptr, nullptr,
                E1, S, nullptr, NV, HD, 512);
        }
        // E2(xe) = segment_sum(T1[vertex], edges)
        gather_sum_k<<<(NE + 3) / 4, blk, 0, stream>>>(E1, adj_e, off_e, E2, NE);
        // E1(ge) = segment_sum(xe[edges], vertex)
        gather_sum_k<<<(NV + 3) / 4, blk, 0, stream>>>(E2, adj_v, off_v, E1, NV);
        // xA = relu(0.5*(deg*(S + b2w3) + ge@W23b) + 0.5*z0 + b3)
        mgemm_k<4, false><<<xcd_grid(NV, 256), blk, 0, stream>>>(E1, (const bf16*)W23bt,
            b3, nullptr, cnt_v, S, z0, b2w3,
            xA, nullptr, nullptr, NV, HD, HD);
        cur = xA;
    }

    // ---- classifier ----
    mgemm_k<1, false><<<xcd_grid(NV, 256), blk, 0, stream>>>(xA, (const bf16*)cw1t,
        cb1, nullptr, nullptr, nullptr, nullptr, nullptr,
        E1, nullptr, nullptr, NV, HD, HD);
    cls_mfma_k<<<(NV + 63) / 64, blk, 0, stream>>>(E1, (const bf16*)cw2t, cb2, out, NV);
}